// Round 11
// baseline (471.841 us; speedup 1.0000x reference)
//
#include <hip/hip_runtime.h>

// FasterGRUTree R10:
//  leaf10: tag/tagp contribution fused into the leaf GEMM as a 2nd unit-set over
//          extended x_leaf [emb|tag|00|tagp|pad] (K=416); x-GEMM shrinks to K=160
//          (h only) -> phase-3 HBM staging eliminated. Batched phase-1 issue.
//  fold10: gi(c+1) double-buffer prefetch (full step of latency cover).
//  prep_kernel: f16 fragment-ordered B sets WL/WI/WT/WX/WH/WN + 16 bias tables.
// Fallback (ws too small): R2 split kernels (proven; uses WI).

typedef _Float16 f16;
typedef _Float16 f16x4 __attribute__((ext_vector_type(4)));
typedef _Float16 f16x8 __attribute__((ext_vector_type(8)));
typedef float f32x4 __attribute__((ext_vector_type(4)));

namespace {

constexpr int NTREE = 20000;
constexpr int CCH   = 8;
constexpr int WORD  = 300;
constexpr int TAGD  = 50;
constexpr int MEMD  = 150;
constexpr int NBLK  = 250;   // fold blocks (80 trees each)
constexpr int LBLK  = 313;   // leaf blocks (64 trees each, last partial)

constexpr int KT_L = 11;     // leaf K tiles (352 over x_ext)
constexpr int KT_T = 4;      // tag/tagp K tiles (kt 9..12 of x_ext)
constexpr int KT_X = 5;      // h K tiles (160)
constexpr int KT_I = 8;      // legacy x_child tiles (fallback)
constexpr int KT_H = 5;
constexpr int KT_N = 5;
constexpr int NTILE = 30;    // 3 gates x 10 j-tiles

constexpr int XS = 424;      // x_ext LDS row stride (f16); (424/2)%32=20 -> good banks
constexpr int HS = 168;      // xch/h LDS row stride

constexpr size_t OFF_WL   = 0;                                         // 11*30*64*16
constexpr size_t OFF_WI   = OFF_WL + (size_t)KT_L * NTILE * 64 * 16;   // 337920 (fallback)
constexpr size_t OFF_WT   = OFF_WI + (size_t)KT_I * NTILE * 64 * 16;   // 583680
constexpr size_t OFF_WX   = OFF_WT + (size_t)KT_T * NTILE * 64 * 16;   // 706560
constexpr size_t OFF_WH   = OFF_WX + (size_t)KT_X * NTILE * 64 * 16;   // 860160
constexpr size_t OFF_WN   = OFF_WH + (size_t)KT_H * NTILE * 64 * 16;   // 1013760
constexpr size_t OFF_BIAS = OFF_WN + (size_t)KT_N * NTILE * 64 * 16;   // 1167360
constexpr size_t OFF_DATA = OFF_BIAS + 16 * 160 * 4;                   // 1177600

// gi region: [c][tg 0..1249][unit = gate*10 + jt][lane][q] f16
constexpr size_t TG_BYTES = 15360;
constexpr size_t C_STRIDE = (size_t)1250 * TG_BYTES;                   // 19,200,000
constexpr size_t GI_BYTES = (size_t)CCH * C_STRIDE;                    // 153,600,000
constexpr size_t WS_R3    = OFF_DATA + GI_BYTES;
constexpr int    HW_S  = 152;
constexpr size_t WS_R2 = OFF_DATA + (size_t)CCH * NTREE * HW_S * 2;

__device__ __forceinline__ float sigmoid_f(float x) {
  return 1.0f / (1.0f + __expf(-x));
}
__device__ __forceinline__ float tanh_f(float x) {
  float ax = fabsf(x);
  float e  = __expf(-2.0f * ax);
  float t  = (1.0f - e) / (1.0f + e);
  return copysignf(t, x);
}

// ---------------- prep ----------------
__global__ void prep_kernel(const float* __restrict__ w_ih_leaf,
                            const float* __restrict__ b_ih_leaf,
                            const float* __restrict__ b_hh_leaf,
                            const float* __restrict__ w_ih_child,
                            const float* __restrict__ w_hh_child,
                            const float* __restrict__ b_ih_child,
                            const float* __restrict__ b_hh_child,
                            const float* __restrict__ w_hh_node,
                            const float* __restrict__ b_ih_node,
                            const float* __restrict__ b_hh_node,
                            char* __restrict__ ws) {
  const int NWL = KT_L * NTILE * 64;  // 21120
  const int NWI = KT_I * NTILE * 64;  // 15360
  const int NWT = KT_T * NTILE * 64;  //  7680
  const int NWX = KT_X * NTILE * 64;  //  9600
  const int NWH = KT_H * NTILE * 64;  //  9600
  const int NWN = KT_N * NTILE * 64;  //  9600
  int t = blockIdx.x * blockDim.x + threadIdx.x;

  if (t < NWL) {  // w_ih_leaf over x_ext cols 0..352 (tag at 300..349; 350,351 zero)
    int kt = t / (NTILE * 64), rem = t % (NTILE * 64);
    int nt = rem / 64, l = rem % 64;
    int gate = nt / 10, jt = nt % 10;
    int j = jt * 16 + (l & 15);
    bool valid = j < MEMD;
    int g = gate * MEMD + (valid ? j : 0);
    f16x8 v;
#pragma unroll
    for (int e = 0; e < 8; ++e) {
      int k = kt * 32 + ((l >> 4) * 8) + e;
      v[e] = (f16)((valid && k < WORD + TAGD) ? w_ih_leaf[g * (WORD + TAGD) + k] : 0.0f);
    }
    ((f16x8*)(ws + OFF_WL))[t] = v;
    return;
  }
  t -= NWL;
  if (t < NWI) {  // legacy x_child remap (fallback): k<150 h | 152..201 tag | 202..251 tagp
    int kt = t / (NTILE * 64), rem = t % (NTILE * 64);
    int nt = rem / 64, l = rem % 64;
    int gate = nt / 10, jt = nt % 10;
    int j = jt * 16 + (l & 15);
    bool valid = j < MEMD;
    int g = gate * MEMD + (valid ? j : 0);
    f16x8 v;
#pragma unroll
    for (int e = 0; e < 8; ++e) {
      int k = kt * 32 + ((l >> 4) * 8) + e;
      int src = (k < 150) ? k : (k >= 152 && k < 252) ? (k - 2) : -1;
      v[e] = (f16)((valid && src >= 0) ? w_ih_child[g * 250 + src] : 0.0f);
    }
    ((f16x8*)(ws + OFF_WI))[t] = v;
    return;
  }
  t -= NWI;
  if (t < NWT) {  // tag/tagp part of w_ih_child over x_ext kt 9..12:
                  // x_ext 300..349 -> w_ih_child col 150..199 (tag)
                  // x_ext 352..401 -> w_ih_child col 200..249 (tagp)
    int kt = t / (NTILE * 64), rem = t % (NTILE * 64);
    int nt = rem / 64, l = rem % 64;
    int gate = nt / 10, jt = nt % 10;
    int j = jt * 16 + (l & 15);
    bool valid = j < MEMD;
    int g = gate * MEMD + (valid ? j : 0);
    f16x8 v;
#pragma unroll
    for (int e = 0; e < 8; ++e) {
      int k = (9 + kt) * 32 + ((l >> 4) * 8) + e;  // 288..416
      float x = 0.0f;
      if (valid) {
        if (k >= 300 && k < 350)      x = w_ih_child[g * 250 + 150 + (k - 300)];
        else if (k >= 352 && k < 402) x = w_ih_child[g * 250 + 200 + (k - 352)];
      }
      v[e] = (f16)x;
    }
    ((f16x8*)(ws + OFF_WT))[t] = v;
    return;
  }
  t -= NWT;
  if (t < NWX) {  // h part of w_ih_child, K=160
    int kt = t / (NTILE * 64), rem = t % (NTILE * 64);
    int nt = rem / 64, l = rem % 64;
    int gate = nt / 10, jt = nt % 10;
    int j = jt * 16 + (l & 15);
    bool valid = j < MEMD;
    int g = gate * MEMD + (valid ? j : 0);
    f16x8 v;
#pragma unroll
    for (int e = 0; e < 8; ++e) {
      int k = kt * 32 + ((l >> 4) * 8) + e;
      v[e] = (f16)((valid && k < MEMD) ? w_ih_child[g * 250 + k] : 0.0f);
    }
    ((f16x8*)(ws + OFF_WX))[t] = v;
    return;
  }
  t -= NWX;
  if (t < NWH) {  // w_hh_child, K=160
    int kt = t / (NTILE * 64), rem = t % (NTILE * 64);
    int nt = rem / 64, l = rem % 64;
    int gate = nt / 10, jt = nt % 10;
    int j = jt * 16 + (l & 15);
    bool valid = j < MEMD;
    int g = gate * MEMD + (valid ? j : 0);
    f16x8 v;
#pragma unroll
    for (int e = 0; e < 8; ++e) {
      int k = kt * 32 + ((l >> 4) * 8) + e;
      v[e] = (f16)((valid && k < MEMD) ? w_hh_child[g * MEMD + k] : 0.0f);
    }
    ((f16x8*)(ws + OFF_WH))[t] = v;
    return;
  }
  t -= NWH;
  if (t < NWN) {  // w_hh_node, K=160
    int kt = t / (NTILE * 64), rem = t % (NTILE * 64);
    int nt = rem / 64, l = rem % 64;
    int gate = nt / 10, jt = nt % 10;
    int j = jt * 16 + (l & 15);
    bool valid = j < MEMD;
    int g = gate * MEMD + (valid ? j : 0);
    f16x8 v;
#pragma unroll
    for (int e = 0; e < 8; ++e) {
      int k = kt * 32 + ((l >> 4) * 8) + e;
      v[e] = (f16)((valid && k < MEMD) ? w_hh_node[g * MEMD + k] : 0.0f);
    }
    ((f16x8*)(ws + OFF_WN))[t] = v;
    return;
  }
  t -= NWN;
  if (t < 16 * 160) {
    int arr = t / 160, j = t % 160;
    float v = 0.0f;
    if (j < MEMD) {
      switch (arr) {
        case 0:  v = b_ih_leaf[j] + b_hh_leaf[j]; break;
        case 1:  v = b_ih_leaf[MEMD + j] + b_hh_leaf[MEMD + j]; break;
        case 2:  v = b_ih_leaf[2 * MEMD + j]; break;
        case 3:  v = b_hh_leaf[2 * MEMD + j]; break;
        case 4:  v = b_ih_child[j] + b_hh_child[j]; break;
        case 5:  v = b_ih_child[MEMD + j] + b_hh_child[MEMD + j]; break;
        case 6:  v = b_ih_child[2 * MEMD + j]; break;
        case 7:  v = b_hh_child[2 * MEMD + j]; break;
        case 8:  v = b_ih_node[j] + b_hh_node[j]; break;
        case 9:  v = b_ih_node[MEMD + j] + b_hh_node[MEMD + j]; break;
        case 10: v = b_ih_node[2 * MEMD + j]; break;
        case 11: v = b_hh_node[2 * MEMD + j]; break;
        case 12: v = b_ih_child[j]; break;
        case 13: v = b_ih_child[MEMD + j]; break;
        case 14: v = b_hh_child[j]; break;
        case 15: v = b_hh_child[MEMD + j]; break;
      }
    }
    ((float*)(ws + OFF_BIAS))[arr * 160 + j] = v;
  }
}

// ---------------- leaf10: BM=64, x_ext K=416, fused tag-GEMM, h-GEMM K=160 ----------------
__global__ __launch_bounds__(640, 1)
void leaf10_kernel(const float* __restrict__ embs,
                   const float* __restrict__ tags,
                   const float* __restrict__ tag_parent,
                   char* __restrict__ ws) {
  __shared__ f16 buf[64 * XS];    // 54272 B; xle stride 424 / xch stride 168 aliased
  f16* xle = buf;
  f16* xch = buf;

  const f16x8* WL   = (const f16x8*)(ws + OFF_WL);
  const f16x8* WT   = (const f16x8*)(ws + OFF_WT);
  const f16x8* WX   = (const f16x8*)(ws + OFF_WX);
  const float* BIAS = (const float*)(ws + OFF_BIAS);

  const int tid = threadIdx.x, lane = tid & 63, w = tid >> 6;  // w: 0..9 = j-tile
  const int blk = blockIdx.x, c = blockIdx.y, t0 = blk * 64;
  const int arow = lane & 15, acol8 = (lane >> 4) * 8, qrow = (lane >> 4) * 4;
  const int j = w * 16 + arow;
  const bool jok = j < MEMD;

  // ---- phase 1: batched issue of ALL staging loads, then write xle
  float4 pe[8];
  float2 ptg[3], ptp[3];
#pragma unroll
  for (int s = 0; s < 8; ++s) {
    int i = tid + 640 * s;
    if (i < 4800) {
      int r = i / 75, k4 = i - r * 75;
      int row = min(t0 + r, NTREE - 1);
      pe[s] = *(const float4*)(embs + ((size_t)row * CCH + c) * WORD + 4 * k4);
    }
  }
#pragma unroll
  for (int s = 0; s < 3; ++s) {
    int i = tid + 640 * s;
    if (i < 1600) {
      int r = i / 25, k2 = i - r * 25;
      int row = min(t0 + r, NTREE - 1);
      ptg[s] = *(const float2*)(tags + ((size_t)row * CCH + c) * TAGD + 2 * k2);
      ptp[s] = *(const float2*)(tag_parent + (size_t)row * TAGD + 2 * k2);
    }
  }
#pragma unroll
  for (int s = 0; s < 8; ++s) {
    int i = tid + 640 * s;
    if (i < 4800) {
      int r = i / 75, k4 = i - r * 75;
      f16* p = xle + r * XS + 4 * k4;
      p[0] = (f16)pe[s].x; p[1] = (f16)pe[s].y; p[2] = (f16)pe[s].z; p[3] = (f16)pe[s].w;
    }
  }
#pragma unroll
  for (int s = 0; s < 3; ++s) {
    int i = tid + 640 * s;
    if (i < 1600) {
      int r = i / 25, k2 = i - r * 25;
      xle[r * XS + 300 + 2 * k2] = (f16)ptg[s].x;
      xle[r * XS + 301 + 2 * k2] = (f16)ptg[s].y;
      xle[r * XS + 352 + 2 * k2] = (f16)ptp[s].x;
      xle[r * XS + 353 + 2 * k2] = (f16)ptp[s].y;
    }
  }
  for (int i = tid; i < 64 * 24; i += 640) {  // zeros: 350,351 and 402..423
    int r = i / 24, k = i - r * 24;
    int col = (k < 2) ? (350 + k) : (400 + k);
    xle[r * XS + col] = (f16)0.0f;
  }
  __syncthreads();  // A: staging visible

  // ---- phase 2: fused GEMM over x_ext: leaf units kt 0..10, tag units kt 9..12
  f32x4 aL[3][4], aT[3][4];
#pragma unroll
  for (int g = 0; g < 3; ++g)
#pragma unroll
    for (int m = 0; m < 4; ++m) { aL[g][m] = 0.f; aT[g][m] = 0.f; }

#pragma unroll
  for (int kt = 0; kt < 13; ++kt) {
    f16x8 a0 = *(const f16x8*)(xle + kt * 32 + acol8 + (arow)      * XS);
    f16x8 a1 = *(const f16x8*)(xle + kt * 32 + acol8 + (16 + arow) * XS);
    f16x8 a2 = *(const f16x8*)(xle + kt * 32 + acol8 + (32 + arow) * XS);
    f16x8 a3 = *(const f16x8*)(xle + kt * 32 + acol8 + (48 + arow) * XS);
    if (kt < KT_L) {
#pragma unroll
      for (int g = 0; g < 3; ++g) {
        f16x8 b = WL[(kt * NTILE + g * 10 + w) * 64 + lane];
        aL[g][0] = __builtin_amdgcn_mfma_f32_16x16x32_f16(a0, b, aL[g][0], 0, 0, 0);
        aL[g][1] = __builtin_amdgcn_mfma_f32_16x16x32_f16(a1, b, aL[g][1], 0, 0, 0);
        aL[g][2] = __builtin_amdgcn_mfma_f32_16x16x32_f16(a2, b, aL[g][2], 0, 0, 0);
        aL[g][3] = __builtin_amdgcn_mfma_f32_16x16x32_f16(a3, b, aL[g][3], 0, 0, 0);
      }
    }
    if (kt >= 9) {
#pragma unroll
      for (int g = 0; g < 3; ++g) {
        f16x8 b = WT[((kt - 9) * NTILE + g * 10 + w) * 64 + lane];
        aT[g][0] = __builtin_amdgcn_mfma_f32_16x16x32_f16(a0, b, aT[g][0], 0, 0, 0);
        aT[g][1] = __builtin_amdgcn_mfma_f32_16x16x32_f16(a1, b, aT[g][1], 0, 0, 0);
        aT[g][2] = __builtin_amdgcn_mfma_f32_16x16x32_f16(a2, b, aT[g][2], 0, 0, 0);
        aT[g][3] = __builtin_amdgcn_mfma_f32_16x16x32_f16(a3, b, aT[g][3], 0, 0, 0);
      }
    }
  }
  __syncthreads();  // B: all xle reads done; buf may be rewritten as xch

  // ---- phase 3: leaf gates -> h into xch cols [0,150); zero cols 150..167
  {
    const float bLr = BIAS[j], bLz = BIAS[160 + j];
    const float bLi = BIAS[320 + j], bLh = BIAS[480 + j];
#pragma unroll
    for (int m = 0; m < 4; ++m)
#pragma unroll
      for (int q = 0; q < 4; ++q) {
        int row = 16 * m + qrow + q;
        float rg = sigmoid_f(aL[0][m][q] + bLr);
        float zg = sigmoid_f(aL[1][m][q] + bLz);
        float ng = tanh_f(aL[2][m][q] + bLi + rg * bLh);
        if (jok) xch[row * HS + j] = (f16)((1.0f - zg) * ng);  // h0 = 0
      }
  }
  for (int i = tid; i < 64 * 18; i += 640) {
    int r = i / 18;
    xch[r * HS + 150 + (i - r * 18)] = (f16)0.0f;
  }
  __syncthreads();  // C: xch ready

  // ---- phase 4: h-GEMM K=160
  f32x4 aX[3][4];
#pragma unroll
  for (int g = 0; g < 3; ++g)
#pragma unroll
    for (int m = 0; m < 4; ++m) aX[g][m] = 0.f;

#pragma unroll
  for (int kt = 0; kt < KT_X; ++kt) {
    f16x8 a0 = *(const f16x8*)(xch + kt * 32 + acol8 + (arow)      * HS);
    f16x8 a1 = *(const f16x8*)(xch + kt * 32 + acol8 + (16 + arow) * HS);
    f16x8 a2 = *(const f16x8*)(xch + kt * 32 + acol8 + (32 + arow) * HS);
    f16x8 a3 = *(const f16x8*)(xch + kt * 32 + acol8 + (48 + arow) * HS);
#pragma unroll
    for (int g = 0; g < 3; ++g) {
      f16x8 b = WX[(kt * NTILE + g * 10 + w) * 64 + lane];
      aX[g][0] = __builtin_amdgcn_mfma_f32_16x16x32_f16(a0, b, aX[g][0], 0, 0, 0);
      aX[g][1] = __builtin_amdgcn_mfma_f32_16x16x32_f16(a1, b, aX[g][1], 0, 0, 0);
      aX[g][2] = __builtin_amdgcn_mfma_f32_16x16x32_f16(a2, b, aX[g][2], 0, 0, 0);
      aX[g][3] = __builtin_amdgcn_mfma_f32_16x16x32_f16(a3, b, aX[g][3], 0, 0, 0);
    }
  }

  // ---- phase 5: gi = aT + aX + b_ih_child, fragment-ordered store (tail-guarded)
  {
    const float bi[3] = {BIAS[12 * 160 + j], BIAS[13 * 160 + j], BIAS[6 * 160 + j]};
#pragma unroll
    for (int m = 0; m < 4; ++m) {
      if (t0 + 16 * m < NTREE) {
        int tg = blk * 4 + m;
        char* base = ws + OFF_DATA + (size_t)c * C_STRIDE + (size_t)tg * TG_BYTES +
                     (size_t)lane * 8;
#pragma unroll
        for (int g = 0; g < 3; ++g) {
          f16x4 v;
#pragma unroll
          for (int q = 0; q < 4; ++q)
            v[q] = (f16)(aT[g][m][q] + aX[g][m][q] + bi[g]);
          *(f16x4*)(base + (size_t)(g * 10 + w) * 512) = v;
        }
      }
    }
  }
}

// ---------------- fold10: gi(c+1) double-buffer, W_hh hoisted, c=0 GEMM skipped ----------------
__global__ __launch_bounds__(640, 1)
void fold10_kernel(const char* __restrict__ ws,
                   float* __restrict__ out) {
  __shared__ f16 hls[80 * HS];    // 26880 B

  const f16x8* WH   = (const f16x8*)(ws + OFF_WH);
  const f16x8* WN   = (const f16x8*)(ws + OFF_WN);
  const float* BIAS = (const float*)(ws + OFF_BIAS);

  const int tid = threadIdx.x, lane = tid & 63, w = tid >> 6;  // w: 0..9
  const int blk = blockIdx.x, t0 = blk * 80;
  const int arow = lane & 15, acol8 = (lane >> 4) * 8, qrow = (lane >> 4) * 4;
  const int j = w * 16 + arow;
  const bool jok = j < MEMD;

  const float bhr = BIAS[14 * 160 + j], bhz = BIAS[15 * 160 + j], bhn = BIAS[7 * 160 + j];
  const float bNr = BIAS[8 * 160 + j],  bNz = BIAS[9 * 160 + j];
  const float bNi = BIAS[10 * 160 + j], bNh = BIAS[11 * 160 + j];

  for (int i = tid; i < 80 * 18; i += 640) {
    int r = i / 18;
    hls[r * HS + 150 + (i - r * 18)] = (f16)0.0f;
  }

  f16x8 whr[5], whz[5], whn[5];
#pragma unroll
  for (int kt = 0; kt < KT_H; ++kt) {
    whr[kt] = WH[(kt * NTILE + w) * 64 + lane];
    whz[kt] = WH[(kt * NTILE + 10 + w) * 64 + lane];
    whn[kt] = WH[(kt * NTILE + 20 + w) * 64 + lane];
  }

  const char* gbase = ws + OFF_DATA + (size_t)(blk * 5) * TG_BYTES +
                      (size_t)w * 512 + (size_t)lane * 8;

  f16x4 gbuf[2][15];
#pragma unroll
  for (int m = 0; m < 5; ++m)
#pragma unroll
    for (int g = 0; g < 3; ++g)
      gbuf[0][m * 3 + g] = *(const f16x4*)(gbase + (size_t)m * TG_BYTES + (size_t)g * 5120);

  f32x4 hp[5];
#pragma unroll
  for (int m = 0; m < 5; ++m) hp[m] = 0.f;

#pragma unroll
  for (int c = 0; c < CCH; ++c) {
    // prefetch gi(c+1): a full step of GEMM+gates+barriers covers its latency
    if (c < CCH - 1) {
#pragma unroll
      for (int m = 0; m < 5; ++m)
#pragma unroll
        for (int g = 0; g < 3; ++g)
          gbuf[(c + 1) & 1][m * 3 + g] =
              *(const f16x4*)(gbase + (size_t)(c + 1) * C_STRIDE +
                              (size_t)m * TG_BYTES + (size_t)g * 5120);
    }

    f32x4 aR[5], aZ[5], aNh[5];
#pragma unroll
    for (int m = 0; m < 5; ++m) { aR[m] = 0.f; aZ[m] = 0.f; aNh[m] = 0.f; }

    if (c != 0) {  // c=0: h=0 -> gh contribution zero; skip GEMM + barrier
#pragma unroll
      for (int kt = 0; kt < KT_H; ++kt) {
        const f16* ab = hls + kt * 32 + acol8;
#pragma unroll
        for (int m = 0; m < 5; ++m) {
          f16x8 a = *(const f16x8*)(ab + (16 * m + arow) * HS);
          aR[m]  = __builtin_amdgcn_mfma_f32_16x16x32_f16(a, whr[kt], aR[m], 0, 0, 0);
          aZ[m]  = __builtin_amdgcn_mfma_f32_16x16x32_f16(a, whz[kt], aZ[m], 0, 0, 0);
          aNh[m] = __builtin_amdgcn_mfma_f32_16x16x32_f16(a, whn[kt], aNh[m], 0, 0, 0);
        }
      }
      __syncthreads();  // B1
    }

#pragma unroll
    for (int m = 0; m < 5; ++m)
#pragma unroll
      for (int q = 0; q < 4; ++q) {
        int row = 16 * m + qrow + q;
        float rg = sigmoid_f((float)gbuf[c & 1][m * 3 + 0][q] + aR[m][q] + bhr);
        float zg = sigmoid_f((float)gbuf[c & 1][m * 3 + 1][q] + aZ[m][q] + bhz);
        float ng = tanh_f((float)gbuf[c & 1][m * 3 + 2][q] + rg * (aNh[m][q] + bhn));
        float h  = (1.0f - zg) * ng + zg * hp[m][q];
        hp[m][q] = h;
        if (jok) hls[row * HS + j] = (f16)h;
      }
    __syncthreads();  // B2
  }

  // node GRU
  f32x4 aR[5], aZ[5], aNh[5];
#pragma unroll
  for (int m = 0; m < 5; ++m) { aR[m] = 0.f; aZ[m] = 0.f; aNh[m] = 0.f; }
  for (int kt = 0; kt < KT_N; ++kt) {
    f16x8 br = WN[(kt * NTILE + w) * 64 + lane];
    f16x8 bz = WN[(kt * NTILE + 10 + w) * 64 + lane];
    f16x8 bn = WN[(kt * NTILE + 20 + w) * 64 + lane];
    const f16* ab = hls + kt * 32 + acol8;
#pragma unroll
    for (int m = 0; m < 5; ++m) {
      f16x8 a = *(const f16x8*)(ab + (16 * m + arow) * HS);
      aR[m]  = __builtin_amdgcn_mfma_f32_16x16x32_f16(a, br, aR[m], 0, 0, 0);
      aZ[m]  = __builtin_amdgcn_mfma_f32_16x16x32_f16(a, bz, aZ[m], 0, 0, 0);
      aNh[m] = __builtin_amdgcn_mfma_f32_16x16x32_f16(a, bn, aNh[m], 0, 0, 0);
    }
  }
#pragma unroll
  for (int m = 0; m < 5; ++m)
#pragma unroll
    for (int q = 0; q < 4; ++q) {
      int row = 16 * m + qrow + q;
      float rg = sigmoid_f(aR[m][q] + bNr);
      float zg = sigmoid_f(aZ[m][q] + bNz);
      float ng = tanh_f(bNi + rg * (aNh[m][q] + bNh));
      float o  = (1.0f - zg) * ng + zg * hp[m][q];
      if (jok) out[(size_t)(t0 + row) * MEMD + j] = o;
    }
}

// ================= R2 fallback (proven; uses WI) =================
namespace r2 {

__global__ __launch_bounds__(640)
void leaf_kernel(const float* __restrict__ embs,
                 const float* __restrict__ tags,
                 char* __restrict__ ws) {
  __shared__ f16 xle[80 * 360];
  const f16x8* WL   = (const f16x8*)(ws + OFF_WL);
  const float* BIAS = (const float*)(ws + OFF_BIAS);
  f16* hws = (f16*)(ws + OFF_DATA);

  const int tid = threadIdx.x, lane = tid & 63, w = tid >> 6;
  const int c = blockIdx.y, t0 = blockIdx.x * 80;
  const int arow = lane & 15, acol8 = (lane >> 4) * 8, qrow = (lane >> 4) * 4;
  const int j = w * 16 + (lane & 15);

  for (int i = tid; i < 80 * 150; i += 640) {
    int r = i / 150, k2 = i - r * 150;
    float2 v = *(const float2*)(embs + ((size_t)(t0 + r) * CCH + c) * WORD + 2 * k2);
    xle[r * 360 + 2 * k2]     = (f16)v.x;
    xle[r * 360 + 2 * k2 + 1] = (f16)v.y;
  }
  for (int i = tid; i < 80 * 25; i += 640) {
    int r = i / 25, k2 = i - r * 25;
    float2 v = *(const float2*)(tags + ((size_t)(t0 + r) * CCH + c) * TAGD + 2 * k2);
    xle[r * 360 + 300 + 2 * k2]     = (f16)v.x;
    xle[r * 360 + 300 + 2 * k2 + 1] = (f16)v.y;
  }
  for (int i = tid; i < 80; i += 640) {
    xle[i * 360 + 350] = (f16)0.0f;
    xle[i * 360 + 351] = (f16)0.0f;
  }
  __syncthreads();

  f32x4 aR[5], aZ[5], aN[5];
#pragma unroll
  for (int m = 0; m < 5; ++m) { aR[m] = 0.f; aZ[m] = 0.f; aN[m] = 0.f; }
  for (int kt = 0; kt < KT_L; ++kt) {
    f16x8 br = WL[(kt * NTILE + w) * 64 + lane];
    f16x8 bz = WL[(kt * NTILE + 10 + w) * 64 + lane];
    f16x8 bn = WL[(kt * NTILE + 20 + w) * 64 + lane];
    const f16* ab = xle + kt * 32 + acol8;
#pragma unroll
    for (int m = 0; m < 5; ++m) {
      f16x8 a = *(const f16x8*)(ab + (16 * m + arow) * 360);
      aR[m] = __builtin_amdgcn_mfma_f32_16x16x32_f16(a, br, aR[m], 0, 0, 0);
      aZ[m] = __builtin_amdgcn_mfma_f32_16x16x32_f16(a, bz, aZ[m], 0, 0, 0);
      aN[m] = __builtin_amdgcn_mfma_f32_16x16x32_f16(a, bn, aN[m], 0, 0, 0);
    }
  }
  const float bLr = BIAS[j], bLz = BIAS[160 + j], bLi = BIAS[320 + j], bLh = BIAS[480 + j];
#pragma unroll
  for (int m = 0; m < 5; ++m) {
#pragma unroll
    for (int q = 0; q < 4; ++q) {
      int row = 16 * m + qrow + q;
      float rg = sigmoid_f(aR[m][q] + bLr);
      float zg = sigmoid_f(aZ[m][q] + bLz);
      float ng = tanh_f(aN[m][q] + bLi + rg * bLh);
      float h  = (1.0f - zg) * ng;
      if (j < HW_S)
        hws[((size_t)c * NTREE + t0 + row) * HW_S + j] = (f16)(j < MEMD ? h : 0.0f);
    }
  }
}

__global__ __launch_bounds__(640)
void fold_kernel(const float* __restrict__ tags,
                 const float* __restrict__ tag_parent,
                 const char* __restrict__ ws,
                 float* __restrict__ out) {
  extern __shared__ char fsm[];
  f16* xch0 = (f16*)fsm;
  f16* xch1 = xch0 + 80 * 264;
  f16* hls  = xch1 + 80 * 264;

  const f16x8* WI   = (const f16x8*)(ws + OFF_WI);
  const f16x8* WH   = (const f16x8*)(ws + OFF_WH);
  const f16x8* WN   = (const f16x8*)(ws + OFF_WN);
  const float* BIAS = (const float*)(ws + OFF_BIAS);
  const f16*   hws  = (const f16*)(ws + OFF_DATA);

  const int tid = threadIdx.x, lane = tid & 63, w = tid >> 6;
  const int t0 = blockIdx.x * 80;
  const int arow = lane & 15, acol8 = (lane >> 4) * 8, qrow = (lane >> 4) * 4;
  const int j = w * 16 + (lane & 15);
  const bool jok = j < MEMD;

  const float bCr = BIAS[4 * 160 + j], bCz = BIAS[5 * 160 + j];
  const float bCi = BIAS[6 * 160 + j], bCh = BIAS[7 * 160 + j];
  const float bNr = BIAS[8 * 160 + j], bNz = BIAS[9 * 160 + j];
  const float bNi = BIAS[10 * 160 + j], bNh = BIAS[11 * 160 + j];

  for (int i = tid; i < 1680; i += 640) ((int4*)hls)[i] = make_int4(0, 0, 0, 0);
  for (int i = tid; i < 80 * 25; i += 640) {
    int r = i / 25, k2 = i - r * 25;
    float2 v = *(const float2*)(tag_parent + (size_t)(t0 + r) * TAGD + 2 * k2);
    f16 a = (f16)v.x, b = (f16)v.y;
    xch0[r * 264 + 202 + 2 * k2] = a; xch0[r * 264 + 203 + 2 * k2] = b;
    xch1[r * 264 + 202 + 2 * k2] = a; xch1[r * 264 + 203 + 2 * k2] = b;
  }
  for (int i = tid; i < 80 * 4; i += 640) {
    int r = i >> 2, k = i & 3;
    xch0[r * 264 + 252 + k] = (f16)0.0f;
    xch1[r * 264 + 252 + k] = (f16)0.0f;
  }
#pragma unroll
  for (int s = 0; s < 3; ++s) {
    int i = tid + 640 * s;
    if (i < 1520) {
      int r = i / 19, q = i - r * 19;
      *(f16x8*)(xch0 + r * 264 + 8 * q) =
          *(const f16x8*)(hws + ((size_t)(t0 + r)) * HW_S + 8 * q);
    }
  }
#pragma unroll
  for (int s = 0; s < 4; ++s) {
    int i = tid + 640 * s;
    if (i < 2000) {
      int r = i / 25, k2 = i - r * 25;
      float2 v = *(const float2*)(tags + ((size_t)(t0 + r) * CCH) * TAGD + 2 * k2);
      xch0[r * 264 + 152 + 2 * k2] = (f16)v.x;
      xch0[r * 264 + 153 + 2 * k2] = (f16)v.y;
    }
  }
  __syncthreads();

  f32x4 hp[5];
#pragma unroll
  for (int m = 0; m < 5; ++m) hp[m] = 0.f;

  f16* xc = xch0;
  f16* xa = xch1;

  for (int c = 0; c < CCH; ++c) {
    f16x8 ph[3];
    float2 pt[4];
    if (c < 7) {
#pragma unroll
      for (int s = 0; s < 3; ++s) {
        int i = tid + 640 * s;
        if (i < 1520) {
          int r = i / 19, q = i - r * 19;
          ph[s] = *(const f16x8*)(hws + ((size_t)(c + 1) * NTREE + t0 + r) * HW_S + 8 * q);
        }
      }
#pragma unroll
      for (int s = 0; s < 4; ++s) {
        int i = tid + 640 * s;
        if (i < 2000) {
          int r = i / 25, k2 = i - r * 25;
          pt[s] = *(const float2*)(tags + ((size_t)(t0 + r) * CCH + (c + 1)) * TAGD + 2 * k2);
        }
      }
    }

    f32x4 aR[5], aZ[5], aNi[5], aNh[5];
#pragma unroll
    for (int m = 0; m < 5; ++m) { aR[m] = 0.f; aZ[m] = 0.f; aNi[m] = 0.f; aNh[m] = 0.f; }
    for (int kt = 0; kt < KT_I; ++kt) {
      f16x8 br = WI[(kt * NTILE + w) * 64 + lane];
      f16x8 bz = WI[(kt * NTILE + 10 + w) * 64 + lane];
      f16x8 bn = WI[(kt * NTILE + 20 + w) * 64 + lane];
      const f16* ab = xc + kt * 32 + acol8;
#pragma unroll
      for (int m = 0; m < 5; ++m) {
        f16x8 a = *(const f16x8*)(ab + (16 * m + arow) * 264);
        aR[m]  = __builtin_amdgcn_mfma_f32_16x16x32_f16(a, br, aR[m], 0, 0, 0);
        aZ[m]  = __builtin_amdgcn_mfma_f32_16x16x32_f16(a, bz, aZ[m], 0, 0, 0);
        aNi[m] = __builtin_amdgcn_mfma_f32_16x16x32_f16(a, bn, aNi[m], 0, 0, 0);
      }
    }
    for (int kt = 0; kt < KT_H; ++kt) {
      f16x8 br = WH[(kt * NTILE + w) * 64 + lane];
      f16x8 bz = WH[(kt * NTILE + 10 + w) * 64 + lane];
      f16x8 bn = WH[(kt * NTILE + 20 + w) * 64 + lane];
      const f16* ab = hls + kt * 32 + acol8;
#pragma unroll
      for (int m = 0; m < 5; ++m) {
        f16x8 a = *(const f16x8*)(ab + (16 * m + arow) * 168);
        aR[m]  = __builtin_amdgcn_mfma_f32_16x16x32_f16(a, br, aR[m], 0, 0, 0);
        aZ[m]  = __builtin_amdgcn_mfma_f32_16x16x32_f16(a, bz, aZ[m], 0, 0, 0);
        aNh[m] = __builtin_amdgcn_mfma_f32_16x16x32_f16(a, bn, aNh[m], 0, 0, 0);
      }
    }
    __syncthreads();

    if (c < 7) {
#pragma unroll
      for (int s = 0; s < 3; ++s) {
        int i = tid + 640 * s;
        if (i < 1520) {
          int r = i / 19, q = i - r * 19;
          *(f16x8*)(xa + r * 264 + 8 * q) = ph[s];
        }
      }
#pragma unroll
      for (int s = 0; s < 4; ++s) {
        int i = tid + 640 * s;
        if (i < 2000) {
          int r = i / 25, k2 = i - r * 25;
          xa[r * 264 + 152 + 2 * k2] = (f16)pt[s].x;
          xa[r * 264 + 153 + 2 * k2] = (f16)pt[s].y;
        }
      }
    }

#pragma unroll
    for (int m = 0; m < 5; ++m) {
#pragma unroll
      for (int q = 0; q < 4; ++q) {
        int row = 16 * m + qrow + q;
        float rg = sigmoid_f(aR[m][q] + bCr);
        float zg = sigmoid_f(aZ[m][q] + bCz);
        float ng = tanh_f(aNi[m][q] + bCi + rg * (aNh[m][q] + bCh));
        float h  = (1.0f - zg) * ng + zg * hp[m][q];
        hp[m][q] = h;
        if (jok) hls[row * 168 + j] = (f16)h;
      }
    }
    __syncthreads();
    f16* tsw = xc; xc = xa; xa = tsw;
  }

  f32x4 aR[5], aZ[5], aNh[5];
#pragma unroll
  for (int m = 0; m < 5; ++m) { aR[m] = 0.f; aZ[m] = 0.f; aNh[m] = 0.f; }
  for (int kt = 0; kt < KT_N; ++kt) {
    f16x8 br = WN[(kt * NTILE + w) * 64 + lane];
    f16x8 bz = WN[(kt * NTILE + 10 + w) * 64 + lane];
    f16x8 bn = WN[(kt * NTILE + 20 + w) * 64 + lane];
    const f16* ab = hls + kt * 32 + acol8;
#pragma unroll
    for (int m = 0; m < 5; ++m) {
      f16x8 a = *(const f16x8*)(ab + (16 * m + arow) * 168);
      aR[m]  = __builtin_amdgcn_mfma_f32_16x16x32_f16(a, br, aR[m], 0, 0, 0);
      aZ[m]  = __builtin_amdgcn_mfma_f32_16x16x32_f16(a, bz, aZ[m], 0, 0, 0);
      aNh[m] = __builtin_amdgcn_mfma_f32_16x16x32_f16(a, bn, aNh[m], 0, 0, 0);
    }
  }
#pragma unroll
  for (int m = 0; m < 5; ++m) {
#pragma unroll
    for (int q = 0; q < 4; ++q) {
      int row = 16 * m + qrow + q;
      float rg = sigmoid_f(aR[m][q] + bNr);
      float zg = sigmoid_f(aZ[m][q] + bNz);
      float ng = tanh_f(bNi + rg * (aNh[m][q] + bNh));
      float o  = (1.0f - zg) * ng + zg * hp[m][q];
      if (jok) out[(size_t)(t0 + row) * MEMD + j] = o;
    }
  }
}

}  // namespace r2

}  // namespace

extern "C" void kernel_launch(void* const* d_in, const int* in_sizes, int n_in,
                              void* d_out, int out_size, void* d_ws, size_t ws_size,
                              hipStream_t stream) {
  const float* embs       = (const float*)d_in[0];
  const float* tags       = (const float*)d_in[1];
  const float* tag_parent = (const float*)d_in[2];
  const float* w_ih_leaf  = (const float*)d_in[3];
  // d_in[4] w_hh_leaf unused (h0 = 0)
  const float* b_ih_leaf  = (const float*)d_in[5];
  const float* b_hh_leaf  = (const float*)d_in[6];
  const float* w_ih_child = (const float*)d_in[7];
  const float* w_hh_child = (const float*)d_in[8];
  const float* b_ih_child = (const float*)d_in[9];
  const float* b_hh_child = (const float*)d_in[10];
  // d_in[11] w_ih_node unused (x = 0)
  const float* w_hh_node  = (const float*)d_in[12];
  const float* b_ih_node  = (const float*)d_in[13];
  const float* b_hh_node  = (const float*)d_in[14];
  float* out = (float*)d_out;
  char*  ws  = (char*)d_ws;

  // prep: 75520 threads (21120+15360+7680+9600+9600+9600+2560)
  prep_kernel<<<295, 256, 0, stream>>>(w_ih_leaf, b_ih_leaf, b_hh_leaf,
                                       w_ih_child, w_hh_child, b_ih_child, b_hh_child,
                                       w_hh_node, b_ih_node, b_hh_node, ws);

  if (ws_size >= WS_R3) {
    leaf10_kernel<<<dim3(LBLK, CCH), 640, 0, stream>>>(embs, tags, tag_parent, ws);
    fold10_kernel<<<NBLK, 640, 0, stream>>>(ws, out);
  } else {
    r2::leaf_kernel<<<dim3(250, CCH), 640, 0, stream>>>(embs, tags, ws);
    constexpr int FOLD_LDS = (2 * 80 * 264 + 80 * 168) * 2;  // 111360
    hipFuncSetAttribute((const void*)r2::fold_kernel,
                        hipFuncAttributeMaxDynamicSharedMemorySize, FOLD_LDS);
    r2::fold_kernel<<<250, 640, FOLD_LDS, stream>>>(tags, tag_parent, ws, out);
  }
}

// Round 12
// 470.551 us; speedup vs baseline: 1.0027x; 1.0027x over previous
//
#include <hip/hip_runtime.h>

// FasterGRUTree R11: best-known base (R9) with two targeted changes:
//  leaf11: TWO children per block, double LDS buffer; c1's staging loads issue
//          during c0's leaf GEMM (T14). Halves block count + exposed staging.
//  fold11: h double-buffered in LDS -> ONE barrier per step (was two).
//  prep_kernel: f16 fragment-ordered WL/WI/WH/WN + 16 bias tables (R9 layout).
// Fallback (ws too small): R2 split kernels (proven).

typedef _Float16 f16;
typedef _Float16 f16x4 __attribute__((ext_vector_type(4)));
typedef _Float16 f16x8 __attribute__((ext_vector_type(8)));
typedef float f32x4 __attribute__((ext_vector_type(4)));

namespace {

constexpr int NTREE = 20000;
constexpr int CCH   = 8;
constexpr int WORD  = 300;
constexpr int TAGD  = 50;
constexpr int MEMD  = 150;
constexpr int NBLK  = 250;   // fold blocks (80 trees each)
constexpr int LBLK  = 313;   // leaf blocks (64 trees each, last partial)

constexpr int KT_L = 11;     // leaf K tiles (352)
constexpr int KT_I = 8;      // x_child K tiles (256 = h|00|tag|tagp|0^4)
constexpr int KT_H = 5;      // hh K tiles (160)
constexpr int KT_N = 5;      // node K tiles (160)
constexpr int NTILE = 30;    // 3 gates x 10 j-tiles

constexpr size_t OFF_WL   = 0;
constexpr size_t OFF_WI   = OFF_WL + (size_t)KT_L * NTILE * 64 * 16;  // 337920
constexpr size_t OFF_WH   = OFF_WI + (size_t)KT_I * NTILE * 64 * 16;  // 583680
constexpr size_t OFF_WN   = OFF_WH + (size_t)KT_H * NTILE * 64 * 16;  // 737280
constexpr size_t OFF_BIAS = OFF_WN + (size_t)KT_N * NTILE * 64 * 16;  // 890880
constexpr size_t OFF_DATA = OFF_BIAS + 16 * 160 * 4;                  // 901120

// gi region: [c][tg 0..1249][unit = gate*10 + jt][lane][q] f16
constexpr size_t TG_BYTES = 15360;   // 30 units x 64 lanes x 8 B
constexpr size_t C_STRIDE = (size_t)1250 * TG_BYTES;                  // 19,200,000
constexpr size_t GI_BYTES = (size_t)CCH * C_STRIDE;                   // 153,600,000
constexpr size_t WS_R3    = OFF_DATA + GI_BYTES;
constexpr int    HW_S  = 152;
constexpr size_t WS_R2 = OFF_DATA + (size_t)CCH * NTREE * HW_S * 2;

// BIAS arrays (16 x 160 f32):
//  0 bL_r(ih+hh) 1 bL_z 2 bL_in 3 bL_hn | 4..7 child sums | 8..11 node | 12 bC_ir 13 bC_iz 14 bC_hr 15 bC_hz

__device__ __forceinline__ float sigmoid_f(float x) {
  return 1.0f / (1.0f + __expf(-x));
}
__device__ __forceinline__ float tanh_f(float x) {
  float ax = fabsf(x);
  float e  = __expf(-2.0f * ax);
  float t  = (1.0f - e) / (1.0f + e);
  return copysignf(t, x);
}

// ---------------- prep ----------------
__global__ void prep_kernel(const float* __restrict__ w_ih_leaf,
                            const float* __restrict__ b_ih_leaf,
                            const float* __restrict__ b_hh_leaf,
                            const float* __restrict__ w_ih_child,
                            const float* __restrict__ w_hh_child,
                            const float* __restrict__ b_ih_child,
                            const float* __restrict__ b_hh_child,
                            const float* __restrict__ w_hh_node,
                            const float* __restrict__ b_ih_node,
                            const float* __restrict__ b_hh_node,
                            char* __restrict__ ws) {
  const int NWL = KT_L * NTILE * 64;  // 21120
  const int NWI = KT_I * NTILE * 64;  // 15360
  const int NWH = KT_H * NTILE * 64;  //  9600
  const int NWN = KT_N * NTILE * 64;  //  9600
  int t = blockIdx.x * blockDim.x + threadIdx.x;

  if (t < NWL) {  // w_ih_leaf, K=352
    int kt = t / (NTILE * 64), rem = t % (NTILE * 64);
    int nt = rem / 64, l = rem % 64;
    int gate = nt / 10, jt = nt % 10;
    int j = jt * 16 + (l & 15);
    bool valid = j < MEMD;
    int g = gate * MEMD + (valid ? j : 0);
    f16x8 v;
#pragma unroll
    for (int e = 0; e < 8; ++e) {
      int k = kt * 32 + ((l >> 4) * 8) + e;
      v[e] = (f16)((valid && k < WORD + TAGD) ? w_ih_leaf[g * (WORD + TAGD) + k] : 0.0f);
    }
    ((f16x8*)(ws + OFF_WL))[t] = v;
    return;
  }
  t -= NWL;
  if (t < NWI) {  // w_ih_child remapped: k<150 h | 152..201 tag | 202..251 tagp
    int kt = t / (NTILE * 64), rem = t % (NTILE * 64);
    int nt = rem / 64, l = rem % 64;
    int gate = nt / 10, jt = nt % 10;
    int j = jt * 16 + (l & 15);
    bool valid = j < MEMD;
    int g = gate * MEMD + (valid ? j : 0);
    f16x8 v;
#pragma unroll
    for (int e = 0; e < 8; ++e) {
      int k = kt * 32 + ((l >> 4) * 8) + e;
      int src = (k < 150) ? k : (k >= 152 && k < 252) ? (k - 2) : -1;
      v[e] = (f16)((valid && src >= 0) ? w_ih_child[g * 250 + src] : 0.0f);
    }
    ((f16x8*)(ws + OFF_WI))[t] = v;
    return;
  }
  t -= NWI;
  if (t < NWH) {  // w_hh_child, K=160
    int kt = t / (NTILE * 64), rem = t % (NTILE * 64);
    int nt = rem / 64, l = rem % 64;
    int gate = nt / 10, jt = nt % 10;
    int j = jt * 16 + (l & 15);
    bool valid = j < MEMD;
    int g = gate * MEMD + (valid ? j : 0);
    f16x8 v;
#pragma unroll
    for (int e = 0; e < 8; ++e) {
      int k = kt * 32 + ((l >> 4) * 8) + e;
      v[e] = (f16)((valid && k < MEMD) ? w_hh_child[g * MEMD + k] : 0.0f);
    }
    ((f16x8*)(ws + OFF_WH))[t] = v;
    return;
  }
  t -= NWH;
  if (t < NWN) {  // w_hh_node, K=160
    int kt = t / (NTILE * 64), rem = t % (NTILE * 64);
    int nt = rem / 64, l = rem % 64;
    int gate = nt / 10, jt = nt % 10;
    int j = jt * 16 + (l & 15);
    bool valid = j < MEMD;
    int g = gate * MEMD + (valid ? j : 0);
    f16x8 v;
#pragma unroll
    for (int e = 0; e < 8; ++e) {
      int k = kt * 32 + ((l >> 4) * 8) + e;
      v[e] = (f16)((valid && k < MEMD) ? w_hh_node[g * MEMD + k] : 0.0f);
    }
    ((f16x8*)(ws + OFF_WN))[t] = v;
    return;
  }
  t -= NWN;
  if (t < 16 * 160) {
    int arr = t / 160, j = t % 160;
    float v = 0.0f;
    if (j < MEMD) {
      switch (arr) {
        case 0:  v = b_ih_leaf[j] + b_hh_leaf[j]; break;
        case 1:  v = b_ih_leaf[MEMD + j] + b_hh_leaf[MEMD + j]; break;
        case 2:  v = b_ih_leaf[2 * MEMD + j]; break;
        case 3:  v = b_hh_leaf[2 * MEMD + j]; break;
        case 4:  v = b_ih_child[j] + b_hh_child[j]; break;
        case 5:  v = b_ih_child[MEMD + j] + b_hh_child[MEMD + j]; break;
        case 6:  v = b_ih_child[2 * MEMD + j]; break;
        case 7:  v = b_hh_child[2 * MEMD + j]; break;
        case 8:  v = b_ih_node[j] + b_hh_node[j]; break;
        case 9:  v = b_ih_node[MEMD + j] + b_hh_node[MEMD + j]; break;
        case 10: v = b_ih_node[2 * MEMD + j]; break;
        case 11: v = b_hh_node[2 * MEMD + j]; break;
        case 12: v = b_ih_child[j]; break;
        case 13: v = b_ih_child[MEMD + j]; break;
        case 14: v = b_hh_child[j]; break;
        case 15: v = b_hh_child[MEMD + j]; break;
      }
    }
    ((float*)(ws + OFF_BIAS))[arr * 160 + j] = v;
  }
}

// ---------------- leaf11: BM=64, TWO children per block, double LDS buffer ----------------
__global__ __launch_bounds__(640, 1)
void leaf11_kernel(const float* __restrict__ embs,
                   const float* __restrict__ tags,
                   const float* __restrict__ tag_parent,
                   char* __restrict__ ws) {
  __shared__ f16 bufA[64 * 360];  // 46080 B: xle(c0) / xch(c0) aliased
  __shared__ f16 bufB[64 * 360];  // 46080 B: xle(c1) / xch(c1) aliased

  const f16x8* WL   = (const f16x8*)(ws + OFF_WL);
  const f16x8* WI   = (const f16x8*)(ws + OFF_WI);
  const float* BIAS = (const float*)(ws + OFF_BIAS);

  const int tid = threadIdx.x, lane = tid & 63, w = tid >> 6;  // w: 0..9 = j-tile
  const int blk = blockIdx.x, t0 = blk * 64;
  const int c0 = blockIdx.y * 2, c1 = c0 + 1;
  const int arow = lane & 15, acol8 = (lane >> 4) * 8, qrow = (lane >> 4) * 4;
  const int j = w * 16 + arow;
  const bool jok = j < MEMD;

  const float bLr = BIAS[j], bLz = BIAS[160 + j];
  const float bLi = BIAS[320 + j], bLh = BIAS[480 + j];
  const float biC[3] = {BIAS[12 * 160 + j], BIAS[13 * 160 + j], BIAS[6 * 160 + j]};

  // tagp (shared by both children): persistent regs
  float2 tp[3];
#pragma unroll
  for (int s = 0; s < 3; ++s) {
    int i = tid + 640 * s;
    tp[s] = make_float2(0.0f, 0.0f);
    if (i < 1600) {
      int r = i / 25, k2 = i - (i / 25) * 25;
      int row = min(t0 + r, NTREE - 1);
      tp[s] = *(const float2*)(tag_parent + (size_t)row * TAGD + 2 * k2);
    }
  }

  // ---- stage c0 into bufA (exposed once per block)
  for (int i = tid; i < 64 * 75; i += 640) {
    int r = i / 75, k4 = i - r * 75;
    int row = min(t0 + r, NTREE - 1);
    float4 v = *(const float4*)(embs + ((size_t)row * CCH + c0) * WORD + 4 * k4);
    f16* p = bufA + r * 360 + 4 * k4;
    p[0] = (f16)v.x; p[1] = (f16)v.y; p[2] = (f16)v.z; p[3] = (f16)v.w;
  }
  for (int i = tid; i < 64 * 25; i += 640) {
    int r = i / 25, k2 = i - r * 25;
    int row = min(t0 + r, NTREE - 1);
    float2 v = *(const float2*)(tags + ((size_t)row * CCH + c0) * TAGD + 2 * k2);
    bufA[r * 360 + 300 + 2 * k2]     = (f16)v.x;
    bufA[r * 360 + 300 + 2 * k2 + 1] = (f16)v.y;
  }
  if (tid < 64) {
    bufA[tid * 360 + 350] = (f16)0.0f;
    bufA[tid * 360 + 351] = (f16)0.0f;
  }
  __syncthreads();  // A0: bufA staged

  // ---- T14: issue c1's staging loads; held in regs across GEMM-L(c0)
  float4 pe[8];
  float2 pt[3];
#pragma unroll
  for (int s = 0; s < 8; ++s) {
    int i = tid + 640 * s;
    if (i < 4800) {
      int r = i / 75, k4 = i - r * 75;
      int row = min(t0 + r, NTREE - 1);
      pe[s] = *(const float4*)(embs + ((size_t)row * CCH + c1) * WORD + 4 * k4);
    }
  }
#pragma unroll
  for (int s = 0; s < 3; ++s) {
    int i = tid + 640 * s;
    if (i < 1600) {
      int r = i / 25, k2 = i - (i / 25) * 25;
      int row = min(t0 + r, NTREE - 1);
      pt[s] = *(const float2*)(tags + ((size_t)row * CCH + c1) * TAGD + 2 * k2);
    }
  }

  f32x4 acc[3][4];

  // ==================== child c0 ====================
#pragma unroll
  for (int g = 0; g < 3; ++g)
#pragma unroll
    for (int m = 0; m < 4; ++m) acc[g][m] = 0.f;
  for (int kt = 0; kt < KT_L; ++kt) {     // GEMM-L(c0), covers c1 load latency
    f16x8 a0 = *(const f16x8*)(bufA + kt * 32 + acol8 + (arow)      * 360);
    f16x8 a1 = *(const f16x8*)(bufA + kt * 32 + acol8 + (16 + arow) * 360);
    f16x8 a2 = *(const f16x8*)(bufA + kt * 32 + acol8 + (32 + arow) * 360);
    f16x8 a3 = *(const f16x8*)(bufA + kt * 32 + acol8 + (48 + arow) * 360);
#pragma unroll
    for (int g = 0; g < 3; ++g) {
      f16x8 b = WL[(kt * NTILE + g * 10 + w) * 64 + lane];
      acc[g][0] = __builtin_amdgcn_mfma_f32_16x16x32_f16(a0, b, acc[g][0], 0, 0, 0);
      acc[g][1] = __builtin_amdgcn_mfma_f32_16x16x32_f16(a1, b, acc[g][1], 0, 0, 0);
      acc[g][2] = __builtin_amdgcn_mfma_f32_16x16x32_f16(a2, b, acc[g][2], 0, 0, 0);
      acc[g][3] = __builtin_amdgcn_mfma_f32_16x16x32_f16(a3, b, acc[g][3], 0, 0, 0);
    }
  }
  __syncthreads();  // B0: bufA(xle) reads done

  // write bufB = xle(c1) from prefetch regs (frees them)
#pragma unroll
  for (int s = 0; s < 8; ++s) {
    int i = tid + 640 * s;
    if (i < 4800) {
      int r = i / 75, k4 = i - (i / 75) * 75;
      f16* p = bufB + r * 360 + 4 * k4;
      p[0] = (f16)pe[s].x; p[1] = (f16)pe[s].y; p[2] = (f16)pe[s].z; p[3] = (f16)pe[s].w;
    }
  }
#pragma unroll
  for (int s = 0; s < 3; ++s) {
    int i = tid + 640 * s;
    if (i < 1600) {
      int r = i / 25, k2 = i - (i / 25) * 25;
      bufB[r * 360 + 300 + 2 * k2]     = (f16)pt[s].x;
      bufB[r * 360 + 300 + 2 * k2 + 1] = (f16)pt[s].y;
    }
  }
  if (tid < 64) {
    bufB[tid * 360 + 350] = (f16)0.0f;
    bufB[tid * 360 + 351] = (f16)0.0f;
  }
  // gates(c0) -> xch0 (alias bufA, stride 264)
#pragma unroll
  for (int m = 0; m < 4; ++m)
#pragma unroll
    for (int q = 0; q < 4; ++q) {
      int row = 16 * m + qrow + q;
      float rg = sigmoid_f(acc[0][m][q] + bLr);
      float zg = sigmoid_f(acc[1][m][q] + bLz);
      float ng = tanh_f(acc[2][m][q] + bLi + rg * bLh);
      if (jok) bufA[row * 264 + j] = (f16)((1.0f - zg) * ng);  // h0 = 0
    }
  // xch0 tags (L2-hot re-read) + tagp + zeros
  for (int i = tid; i < 64 * 25; i += 640) {
    int r = i / 25, k2 = i - r * 25;
    int row = min(t0 + r, NTREE - 1);
    float2 v = *(const float2*)(tags + ((size_t)row * CCH + c0) * TAGD + 2 * k2);
    bufA[r * 264 + 152 + 2 * k2] = (f16)v.x;
    bufA[r * 264 + 153 + 2 * k2] = (f16)v.y;
  }
#pragma unroll
  for (int s = 0; s < 3; ++s) {
    int i = tid + 640 * s;
    if (i < 1600) {
      int r = i / 25, k2 = i - (i / 25) * 25;
      bufA[r * 264 + 202 + 2 * k2] = (f16)tp[s].x;
      bufA[r * 264 + 203 + 2 * k2] = (f16)tp[s].y;
    }
  }
  for (int i = tid; i < 64 * 6; i += 640) {
    int r = i / 6, k = i - r * 6;
    int col = (k < 2) ? (150 + k) : (250 + k);
    bufA[r * 264 + col] = (f16)0.0f;
  }
  __syncthreads();  // C0: xch0 + xle1 ready

  // GEMM-X(c0) over xch0 (K=256)
#pragma unroll
  for (int g = 0; g < 3; ++g)
#pragma unroll
    for (int m = 0; m < 4; ++m) acc[g][m] = 0.f;
  for (int kt = 0; kt < KT_I; ++kt) {
    f16x8 a0 = *(const f16x8*)(bufA + kt * 32 + acol8 + (arow)      * 264);
    f16x8 a1 = *(const f16x8*)(bufA + kt * 32 + acol8 + (16 + arow) * 264);
    f16x8 a2 = *(const f16x8*)(bufA + kt * 32 + acol8 + (32 + arow) * 264);
    f16x8 a3 = *(const f16x8*)(bufA + kt * 32 + acol8 + (48 + arow) * 264);
#pragma unroll
    for (int g = 0; g < 3; ++g) {
      f16x8 b = WI[(kt * NTILE + g * 10 + w) * 64 + lane];
      acc[g][0] = __builtin_amdgcn_mfma_f32_16x16x32_f16(a0, b, acc[g][0], 0, 0, 0);
      acc[g][1] = __builtin_amdgcn_mfma_f32_16x16x32_f16(a1, b, acc[g][1], 0, 0, 0);
      acc[g][2] = __builtin_amdgcn_mfma_f32_16x16x32_f16(a2, b, acc[g][2], 0, 0, 0);
      acc[g][3] = __builtin_amdgcn_mfma_f32_16x16x32_f16(a3, b, acc[g][3], 0, 0, 0);
    }
  }
  // gi(c0) store (consumes acc before c1 reuses it)
#pragma unroll
  for (int m = 0; m < 4; ++m) {
    if (t0 + 16 * m < NTREE) {
      int tg = blk * 4 + m;
      char* base = ws + OFF_DATA + (size_t)c0 * C_STRIDE + (size_t)tg * TG_BYTES +
                   (size_t)lane * 8;
#pragma unroll
      for (int g = 0; g < 3; ++g) {
        f16x4 v;
#pragma unroll
        for (int q = 0; q < 4; ++q) v[q] = (f16)(acc[g][m][q] + biC[g]);
        *(f16x4*)(base + (size_t)(g * 10 + w) * 512) = v;
      }
    }
  }

  // ==================== child c1 ====================
#pragma unroll
  for (int g = 0; g < 3; ++g)
#pragma unroll
    for (int m = 0; m < 4; ++m) acc[g][m] = 0.f;
  for (int kt = 0; kt < KT_L; ++kt) {     // GEMM-L(c1) over bufB (no barrier needed)
    f16x8 a0 = *(const f16x8*)(bufB + kt * 32 + acol8 + (arow)      * 360);
    f16x8 a1 = *(const f16x8*)(bufB + kt * 32 + acol8 + (16 + arow) * 360);
    f16x8 a2 = *(const f16x8*)(bufB + kt * 32 + acol8 + (32 + arow) * 360);
    f16x8 a3 = *(const f16x8*)(bufB + kt * 32 + acol8 + (48 + arow) * 360);
#pragma unroll
    for (int g = 0; g < 3; ++g) {
      f16x8 b = WL[(kt * NTILE + g * 10 + w) * 64 + lane];
      acc[g][0] = __builtin_amdgcn_mfma_f32_16x16x32_f16(a0, b, acc[g][0], 0, 0, 0);
      acc[g][1] = __builtin_amdgcn_mfma_f32_16x16x32_f16(a1, b, acc[g][1], 0, 0, 0);
      acc[g][2] = __builtin_amdgcn_mfma_f32_16x16x32_f16(a2, b, acc[g][2], 0, 0, 0);
      acc[g][3] = __builtin_amdgcn_mfma_f32_16x16x32_f16(a3, b, acc[g][3], 0, 0, 0);
    }
  }
  __syncthreads();  // B1: bufB(xle) reads done

  // gates(c1) -> xch1 (alias bufB) + tags(c1 from pt) + tagp + zeros
#pragma unroll
  for (int m = 0; m < 4; ++m)
#pragma unroll
    for (int q = 0; q < 4; ++q) {
      int row = 16 * m + qrow + q;
      float rg = sigmoid_f(acc[0][m][q] + bLr);
      float zg = sigmoid_f(acc[1][m][q] + bLz);
      float ng = tanh_f(acc[2][m][q] + bLi + rg * bLh);
      if (jok) bufB[row * 264 + j] = (f16)((1.0f - zg) * ng);
    }
#pragma unroll
  for (int s = 0; s < 3; ++s) {
    int i = tid + 640 * s;
    if (i < 1600) {
      int r = i / 25, k2 = i - (i / 25) * 25;
      bufB[r * 264 + 152 + 2 * k2] = (f16)pt[s].x;
      bufB[r * 264 + 153 + 2 * k2] = (f16)pt[s].y;
      bufB[r * 264 + 202 + 2 * k2] = (f16)tp[s].x;
      bufB[r * 264 + 203 + 2 * k2] = (f16)tp[s].y;
    }
  }
  for (int i = tid; i < 64 * 6; i += 640) {
    int r = i / 6, k = i - r * 6;
    int col = (k < 2) ? (150 + k) : (250 + k);
    bufB[r * 264 + col] = (f16)0.0f;
  }
  __syncthreads();  // C1: xch1 ready

#pragma unroll
  for (int g = 0; g < 3; ++g)
#pragma unroll
    for (int m = 0; m < 4; ++m) acc[g][m] = 0.f;
  for (int kt = 0; kt < KT_I; ++kt) {     // GEMM-X(c1)
    f16x8 a0 = *(const f16x8*)(bufB + kt * 32 + acol8 + (arow)      * 264);
    f16x8 a1 = *(const f16x8*)(bufB + kt * 32 + acol8 + (16 + arow) * 264);
    f16x8 a2 = *(const f16x8*)(bufB + kt * 32 + acol8 + (32 + arow) * 264);
    f16x8 a3 = *(const f16x8*)(bufB + kt * 32 + acol8 + (48 + arow) * 264);
#pragma unroll
    for (int g = 0; g < 3; ++g) {
      f16x8 b = WI[(kt * NTILE + g * 10 + w) * 64 + lane];
      acc[g][0] = __builtin_amdgcn_mfma_f32_16x16x32_f16(a0, b, acc[g][0], 0, 0, 0);
      acc[g][1] = __builtin_amdgcn_mfma_f32_16x16x32_f16(a1, b, acc[g][1], 0, 0, 0);
      acc[g][2] = __builtin_amdgcn_mfma_f32_16x16x32_f16(a2, b, acc[g][2], 0, 0, 0);
      acc[g][3] = __builtin_amdgcn_mfma_f32_16x16x32_f16(a3, b, acc[g][3], 0, 0, 0);
    }
  }
#pragma unroll
  for (int m = 0; m < 4; ++m) {           // gi(c1) store
    if (t0 + 16 * m < NTREE) {
      int tg = blk * 4 + m;
      char* base = ws + OFF_DATA + (size_t)c1 * C_STRIDE + (size_t)tg * TG_BYTES +
                   (size_t)lane * 8;
#pragma unroll
      for (int g = 0; g < 3; ++g) {
        f16x4 v;
#pragma unroll
        for (int q = 0; q < 4; ++q) v[q] = (f16)(acc[g][m][q] + biC[g]);
        *(f16x4*)(base + (size_t)(g * 10 + w) * 512) = v;
      }
    }
  }
}

// ---------------- fold11: h double-buffer -> ONE barrier per step ----------------
__global__ __launch_bounds__(640, 1)
void fold11_kernel(const char* __restrict__ ws,
                   float* __restrict__ out) {
  __shared__ f16 hls[2 * 80 * 168];   // 53760 B; step c reads buf[c&1], writes buf[(c+1)&1]

  const f16x8* WH   = (const f16x8*)(ws + OFF_WH);
  const f16x8* WN   = (const f16x8*)(ws + OFF_WN);
  const float* BIAS = (const float*)(ws + OFF_BIAS);

  const int tid = threadIdx.x, lane = tid & 63, w = tid >> 6;  // w: 0..9
  const int blk = blockIdx.x, t0 = blk * 80;
  const int arow = lane & 15, acol8 = (lane >> 4) * 8, qrow = (lane >> 4) * 4;
  const int j = w * 16 + arow;
  const bool jok = j < MEMD;

  const float bhr = BIAS[14 * 160 + j], bhz = BIAS[15 * 160 + j], bhn = BIAS[7 * 160 + j];
  const float bNr = BIAS[8 * 160 + j],  bNz = BIAS[9 * 160 + j];
  const float bNi = BIAS[10 * 160 + j], bNh = BIAS[11 * 160 + j];

  // zero pad cols 150..167 in BOTH buffers (never h-written; gates cover the rest)
  for (int i = tid; i < 2 * 80 * 18; i += 640) {
    int b = i / (80 * 18), rem = i - b * (80 * 18);
    int r = rem / 18;
    hls[b * 80 * 168 + r * 168 + 150 + (rem - r * 18)] = (f16)0.0f;
  }

  f16x8 whr[5], whz[5], whn[5];
#pragma unroll
  for (int kt = 0; kt < KT_H; ++kt) {
    whr[kt] = WH[(kt * NTILE + w) * 64 + lane];
    whz[kt] = WH[(kt * NTILE + 10 + w) * 64 + lane];
    whn[kt] = WH[(kt * NTILE + 20 + w) * 64 + lane];
  }

  const char* gbase = ws + OFF_DATA + (size_t)(blk * 5) * TG_BYTES +
                      (size_t)w * 512 + (size_t)lane * 8;

  f32x4 hp[5];
#pragma unroll
  for (int m = 0; m < 5; ++m) hp[m] = 0.f;

#pragma unroll
  for (int c = 0; c < CCH; ++c) {
    // gi(c) loads; GEMM below covers their latency
    f16x4 gbuf[15];
#pragma unroll
    for (int m = 0; m < 5; ++m)
#pragma unroll
      for (int g = 0; g < 3; ++g)
        gbuf[m * 3 + g] = *(const f16x4*)(gbase + (size_t)c * C_STRIDE +
                                          (size_t)m * TG_BYTES + (size_t)g * 5120);

    const f16* hcur = hls + (c & 1) * 80 * 168;
    f16*       hnxt = hls + ((c + 1) & 1) * 80 * 168;

    f32x4 aR[5], aZ[5], aNh[5];
#pragma unroll
    for (int m = 0; m < 5; ++m) { aR[m] = 0.f; aZ[m] = 0.f; aNh[m] = 0.f; }

    if (c != 0) {  // c=0: h=0 -> gh contribution zero; skip GEMM
#pragma unroll
      for (int kt = 0; kt < KT_H; ++kt) {
        const f16* ab = hcur + kt * 32 + acol8;
#pragma unroll
        for (int m = 0; m < 5; ++m) {
          f16x8 a = *(const f16x8*)(ab + (16 * m + arow) * 168);
          aR[m]  = __builtin_amdgcn_mfma_f32_16x16x32_f16(a, whr[kt], aR[m], 0, 0, 0);
          aZ[m]  = __builtin_amdgcn_mfma_f32_16x16x32_f16(a, whz[kt], aZ[m], 0, 0, 0);
          aNh[m] = __builtin_amdgcn_mfma_f32_16x16x32_f16(a, whn[kt], aNh[m], 0, 0, 0);
        }
      }
    }

    // gates: write NEW h to the OTHER buffer (prev step's barrier separates the
    // WAR vs step c-1's GEMM reads of hnxt)
#pragma unroll
    for (int m = 0; m < 5; ++m)
#pragma unroll
      for (int q = 0; q < 4; ++q) {
        int row = 16 * m + qrow + q;
        float rg = sigmoid_f((float)gbuf[m * 3 + 0][q] + aR[m][q] + bhr);
        float zg = sigmoid_f((float)gbuf[m * 3 + 1][q] + aZ[m][q] + bhz);
        float ng = tanh_f((float)gbuf[m * 3 + 2][q] + rg * (aNh[m][q] + bhn));
        float h  = (1.0f - zg) * ng + zg * hp[m][q];
        hp[m][q] = h;
        if (jok) hnxt[row * 168 + j] = (f16)h;
      }
    __syncthreads();  // single barrier per step
  }

  // node GRU: h lives in buf[8&1] = buf0
  const f16* hfin = hls;
  f32x4 aR[5], aZ[5], aNh[5];
#pragma unroll
  for (int m = 0; m < 5; ++m) { aR[m] = 0.f; aZ[m] = 0.f; aNh[m] = 0.f; }
  for (int kt = 0; kt < KT_N; ++kt) {
    f16x8 br = WN[(kt * NTILE + w) * 64 + lane];
    f16x8 bz = WN[(kt * NTILE + 10 + w) * 64 + lane];
    f16x8 bn = WN[(kt * NTILE + 20 + w) * 64 + lane];
    const f16* ab = hfin + kt * 32 + acol8;
#pragma unroll
    for (int m = 0; m < 5; ++m) {
      f16x8 a = *(const f16x8*)(ab + (16 * m + arow) * 168);
      aR[m]  = __builtin_amdgcn_mfma_f32_16x16x32_f16(a, br, aR[m], 0, 0, 0);
      aZ[m]  = __builtin_amdgcn_mfma_f32_16x16x32_f16(a, bz, aZ[m], 0, 0, 0);
      aNh[m] = __builtin_amdgcn_mfma_f32_16x16x32_f16(a, bn, aNh[m], 0, 0, 0);
    }
  }
#pragma unroll
  for (int m = 0; m < 5; ++m)
#pragma unroll
    for (int q = 0; q < 4; ++q) {
      int row = 16 * m + qrow + q;
      float rg = sigmoid_f(aR[m][q] + bNr);
      float zg = sigmoid_f(aZ[m][q] + bNz);
      float ng = tanh_f(bNi + rg * (aNh[m][q] + bNh));
      float o  = (1.0f - zg) * ng + zg * hp[m][q];
      if (jok) out[(size_t)(t0 + row) * MEMD + j] = o;
    }
}

// ================= R2 fallback (proven) =================
namespace r2 {

__global__ __launch_bounds__(640)
void leaf_kernel(const float* __restrict__ embs,
                 const float* __restrict__ tags,
                 char* __restrict__ ws) {
  __shared__ f16 xle[80 * 360];
  const f16x8* WL   = (const f16x8*)(ws + OFF_WL);
  const float* BIAS = (const float*)(ws + OFF_BIAS);
  f16* hws = (f16*)(ws + OFF_DATA);

  const int tid = threadIdx.x, lane = tid & 63, w = tid >> 6;
  const int c = blockIdx.y, t0 = blockIdx.x * 80;
  const int arow = lane & 15, acol8 = (lane >> 4) * 8, qrow = (lane >> 4) * 4;
  const int j = w * 16 + (lane & 15);

  for (int i = tid; i < 80 * 150; i += 640) {
    int r = i / 150, k2 = i - r * 150;
    float2 v = *(const float2*)(embs + ((size_t)(t0 + r) * CCH + c) * WORD + 2 * k2);
    xle[r * 360 + 2 * k2]     = (f16)v.x;
    xle[r * 360 + 2 * k2 + 1] = (f16)v.y;
  }
  for (int i = tid; i < 80 * 25; i += 640) {
    int r = i / 25, k2 = i - r * 25;
    float2 v = *(const float2*)(tags + ((size_t)(t0 + r) * CCH + c) * TAGD + 2 * k2);
    xle[r * 360 + 300 + 2 * k2]     = (f16)v.x;
    xle[r * 360 + 300 + 2 * k2 + 1] = (f16)v.y;
  }
  for (int i = tid; i < 80; i += 640) {
    xle[i * 360 + 350] = (f16)0.0f;
    xle[i * 360 + 351] = (f16)0.0f;
  }
  __syncthreads();

  f32x4 aR[5], aZ[5], aN[5];
#pragma unroll
  for (int m = 0; m < 5; ++m) { aR[m] = 0.f; aZ[m] = 0.f; aN[m] = 0.f; }
  for (int kt = 0; kt < KT_L; ++kt) {
    f16x8 br = WL[(kt * NTILE + w) * 64 + lane];
    f16x8 bz = WL[(kt * NTILE + 10 + w) * 64 + lane];
    f16x8 bn = WL[(kt * NTILE + 20 + w) * 64 + lane];
    const f16* ab = xle + kt * 32 + acol8;
#pragma unroll
    for (int m = 0; m < 5; ++m) {
      f16x8 a = *(const f16x8*)(ab + (16 * m + arow) * 360);
      aR[m] = __builtin_amdgcn_mfma_f32_16x16x32_f16(a, br, aR[m], 0, 0, 0);
      aZ[m] = __builtin_amdgcn_mfma_f32_16x16x32_f16(a, bz, aZ[m], 0, 0, 0);
      aN[m] = __builtin_amdgcn_mfma_f32_16x16x32_f16(a, bn, aN[m], 0, 0, 0);
    }
  }
  const float bLr = BIAS[j], bLz = BIAS[160 + j], bLi = BIAS[320 + j], bLh = BIAS[480 + j];
#pragma unroll
  for (int m = 0; m < 5; ++m) {
#pragma unroll
    for (int q = 0; q < 4; ++q) {
      int row = 16 * m + qrow + q;
      float rg = sigmoid_f(aR[m][q] + bLr);
      float zg = sigmoid_f(aZ[m][q] + bLz);
      float ng = tanh_f(aN[m][q] + bLi + rg * bLh);
      float h  = (1.0f - zg) * ng;
      if (j < HW_S)
        hws[((size_t)c * NTREE + t0 + row) * HW_S + j] = (f16)(j < MEMD ? h : 0.0f);
    }
  }
}

__global__ __launch_bounds__(640)
void fold_kernel(const float* __restrict__ tags,
                 const float* __restrict__ tag_parent,
                 const char* __restrict__ ws,
                 float* __restrict__ out) {
  extern __shared__ char fsm[];
  f16* xch0 = (f16*)fsm;
  f16* xch1 = xch0 + 80 * 264;
  f16* hls  = xch1 + 80 * 264;

  const f16x8* WI   = (const f16x8*)(ws + OFF_WI);
  const f16x8* WH   = (const f16x8*)(ws + OFF_WH);
  const f16x8* WN   = (const f16x8*)(ws + OFF_WN);
  const float* BIAS = (const float*)(ws + OFF_BIAS);
  const f16*   hws  = (const f16*)(ws + OFF_DATA);

  const int tid = threadIdx.x, lane = tid & 63, w = tid >> 6;
  const int t0 = blockIdx.x * 80;
  const int arow = lane & 15, acol8 = (lane >> 4) * 8, qrow = (lane >> 4) * 4;
  const int j = w * 16 + (lane & 15);
  const bool jok = j < MEMD;

  const float bCr = BIAS[4 * 160 + j], bCz = BIAS[5 * 160 + j];
  const float bCi = BIAS[6 * 160 + j], bCh = BIAS[7 * 160 + j];
  const float bNr = BIAS[8 * 160 + j], bNz = BIAS[9 * 160 + j];
  const float bNi = BIAS[10 * 160 + j], bNh = BIAS[11 * 160 + j];

  for (int i = tid; i < 1680; i += 640) ((int4*)hls)[i] = make_int4(0, 0, 0, 0);
  for (int i = tid; i < 80 * 25; i += 640) {
    int r = i / 25, k2 = i - r * 25;
    float2 v = *(const float2*)(tag_parent + (size_t)(t0 + r) * TAGD + 2 * k2);
    f16 a = (f16)v.x, b = (f16)v.y;
    xch0[r * 264 + 202 + 2 * k2] = a; xch0[r * 264 + 203 + 2 * k2] = b;
    xch1[r * 264 + 202 + 2 * k2] = a; xch1[r * 264 + 203 + 2 * k2] = b;
  }
  for (int i = tid; i < 80 * 4; i += 640) {
    int r = i >> 2, k = i & 3;
    xch0[r * 264 + 252 + k] = (f16)0.0f;
    xch1[r * 264 + 252 + k] = (f16)0.0f;
  }
#pragma unroll
  for (int s = 0; s < 3; ++s) {
    int i = tid + 640 * s;
    if (i < 1520) {
      int r = i / 19, q = i - r * 19;
      *(f16x8*)(xch0 + r * 264 + 8 * q) =
          *(const f16x8*)(hws + ((size_t)(t0 + r)) * HW_S + 8 * q);
    }
  }
#pragma unroll
  for (int s = 0; s < 4; ++s) {
    int i = tid + 640 * s;
    if (i < 2000) {
      int r = i / 25, k2 = i - r * 25;
      float2 v = *(const float2*)(tags + ((size_t)(t0 + r) * CCH) * TAGD + 2 * k2);
      xch0[r * 264 + 152 + 2 * k2] = (f16)v.x;
      xch0[r * 264 + 153 + 2 * k2] = (f16)v.y;
    }
  }
  __syncthreads();

  f32x4 hp[5];
#pragma unroll
  for (int m = 0; m < 5; ++m) hp[m] = 0.f;

  f16* xc = xch0;
  f16* xa = xch1;

  for (int c = 0; c < CCH; ++c) {
    f16x8 ph[3];
    float2 pt[4];
    if (c < 7) {
#pragma unroll
      for (int s = 0; s < 3; ++s) {
        int i = tid + 640 * s;
        if (i < 1520) {
          int r = i / 19, q = i - r * 19;
          ph[s] = *(const f16x8*)(hws + ((size_t)(c + 1) * NTREE + t0 + r) * HW_S + 8 * q);
        }
      }
#pragma unroll
      for (int s = 0; s < 4; ++s) {
        int i = tid + 640 * s;
        if (i < 2000) {
          int r = i / 25, k2 = i - r * 25;
          pt[s] = *(const float2*)(tags + ((size_t)(t0 + r) * CCH + (c + 1)) * TAGD + 2 * k2);
        }
      }
    }

    f32x4 aR[5], aZ[5], aNi[5], aNh[5];
#pragma unroll
    for (int m = 0; m < 5; ++m) { aR[m] = 0.f; aZ[m] = 0.f; aNi[m] = 0.f; aNh[m] = 0.f; }
    for (int kt = 0; kt < KT_I; ++kt) {
      f16x8 br = WI[(kt * NTILE + w) * 64 + lane];
      f16x8 bz = WI[(kt * NTILE + 10 + w) * 64 + lane];
      f16x8 bn = WI[(kt * NTILE + 20 + w) * 64 + lane];
      const f16* ab = xc + kt * 32 + acol8;
#pragma unroll
      for (int m = 0; m < 5; ++m) {
        f16x8 a = *(const f16x8*)(ab + (16 * m + arow) * 264);
        aR[m]  = __builtin_amdgcn_mfma_f32_16x16x32_f16(a, br, aR[m], 0, 0, 0);
        aZ[m]  = __builtin_amdgcn_mfma_f32_16x16x32_f16(a, bz, aZ[m], 0, 0, 0);
        aNi[m] = __builtin_amdgcn_mfma_f32_16x16x32_f16(a, bn, aNi[m], 0, 0, 0);
      }
    }
    for (int kt = 0; kt < KT_H; ++kt) {
      f16x8 br = WH[(kt * NTILE + w) * 64 + lane];
      f16x8 bz = WH[(kt * NTILE + 10 + w) * 64 + lane];
      f16x8 bn = WH[(kt * NTILE + 20 + w) * 64 + lane];
      const f16* ab = hls + kt * 32 + acol8;
#pragma unroll
      for (int m = 0; m < 5; ++m) {
        f16x8 a = *(const f16x8*)(ab + (16 * m + arow) * 168);
        aR[m]  = __builtin_amdgcn_mfma_f32_16x16x32_f16(a, br, aR[m], 0, 0, 0);
        aZ[m]  = __builtin_amdgcn_mfma_f32_16x16x32_f16(a, bz, aZ[m], 0, 0, 0);
        aNh[m] = __builtin_amdgcn_mfma_f32_16x16x32_f16(a, bn, aNh[m], 0, 0, 0);
      }
    }
    __syncthreads();

    if (c < 7) {
#pragma unroll
      for (int s = 0; s < 3; ++s) {
        int i = tid + 640 * s;
        if (i < 1520) {
          int r = i / 19, q = i - r * 19;
          *(f16x8*)(xa + r * 264 + 8 * q) = ph[s];
        }
      }
#pragma unroll
      for (int s = 0; s < 4; ++s) {
        int i = tid + 640 * s;
        if (i < 2000) {
          int r = i / 25, k2 = i - r * 25;
          xa[r * 264 + 152 + 2 * k2] = (f16)pt[s].x;
          xa[r * 264 + 153 + 2 * k2] = (f16)pt[s].y;
        }
      }
    }

#pragma unroll
    for (int m = 0; m < 5; ++m) {
#pragma unroll
      for (int q = 0; q < 4; ++q) {
        int row = 16 * m + qrow + q;
        float rg = sigmoid_f(aR[m][q] + bCr);
        float zg = sigmoid_f(aZ[m][q] + bCz);
        float ng = tanh_f(aNi[m][q] + bCi + rg * (aNh[m][q] + bCh));
        float h  = (1.0f - zg) * ng + zg * hp[m][q];
        hp[m][q] = h;
        if (jok) hls[row * 168 + j] = (f16)h;
      }
    }
    __syncthreads();
    f16* tsw = xc; xc = xa; xa = tsw;
  }

  f32x4 aR[5], aZ[5], aNh[5];
#pragma unroll
  for (int m = 0; m < 5; ++m) { aR[m] = 0.f; aZ[m] = 0.f; aNh[m] = 0.f; }
  for (int kt = 0; kt < KT_N; ++kt) {
    f16x8 br = WN[(kt * NTILE + w) * 64 + lane];
    f16x8 bz = WN[(kt * NTILE + 10 + w) * 64 + lane];
    f16x8 bn = WN[(kt * NTILE + 20 + w) * 64 + lane];
    const f16* ab = hls + kt * 32 + acol8;
#pragma unroll
    for (int m = 0; m < 5; ++m) {
      f16x8 a = *(const f16x8*)(ab + (16 * m + arow) * 168);
      aR[m]  = __builtin_amdgcn_mfma_f32_16x16x32_f16(a, br, aR[m], 0, 0, 0);
      aZ[m]  = __builtin_amdgcn_mfma_f32_16x16x32_f16(a, bz, aZ[m], 0, 0, 0);
      aNh[m] = __builtin_amdgcn_mfma_f32_16x16x32_f16(a, bn, aNh[m], 0, 0, 0);
    }
  }
#pragma unroll
  for (int m = 0; m < 5; ++m) {
#pragma unroll
    for (int q = 0; q < 4; ++q) {
      int row = 16 * m + qrow + q;
      float rg = sigmoid_f(aR[m][q] + bNr);
      float zg = sigmoid_f(aZ[m][q] + bNz);
      float ng = tanh_f(bNi + rg * (aNh[m][q] + bNh));
      float o  = (1.0f - zg) * ng + zg * hp[m][q];
      if (jok) out[(size_t)(t0 + row) * MEMD + j] = o;
    }
  }
}

}  // namespace r2

}  // namespace

extern "C" void kernel_launch(void* const* d_in, const int* in_sizes, int n_in,
                              void* d_out, int out_size, void* d_ws, size_t ws_size,
                              hipStream_t stream) {
  const float* embs       = (const float*)d_in[0];
  const float* tags       = (const float*)d_in[1];
  const float* tag_parent = (const float*)d_in[2];
  const float* w_ih_leaf  = (const float*)d_in[3];
  // d_in[4] w_hh_leaf unused (h0 = 0)
  const float* b_ih_leaf  = (const float*)d_in[5];
  const float* b_hh_leaf  = (const float*)d_in[6];
  const float* w_ih_child = (const float*)d_in[7];
  const float* w_hh_child = (const float*)d_in[8];
  const float* b_ih_child = (const float*)d_in[9];
  const float* b_hh_child = (const float*)d_in[10];
  // d_in[11] w_ih_node unused (x = 0)
  const float* w_hh_node  = (const float*)d_in[12];
  const float* b_ih_node  = (const float*)d_in[13];
  const float* b_hh_node  = (const float*)d_in[14];
  float* out = (float*)d_out;
  char*  ws  = (char*)d_ws;

  prep_kernel<<<228, 256, 0, stream>>>(w_ih_leaf, b_ih_leaf, b_hh_leaf,
                                       w_ih_child, w_hh_child, b_ih_child, b_hh_child,
                                       w_hh_node, b_ih_node, b_hh_node, ws);

  if (ws_size >= WS_R3) {
    leaf11_kernel<<<dim3(LBLK, CCH / 2), 640, 0, stream>>>(embs, tags, tag_parent, ws);
    fold11_kernel<<<NBLK, 640, 0, stream>>>(ws, out);
  } else {
    r2::leaf_kernel<<<dim3(250, CCH), 640, 0, stream>>>(embs, tags, ws);
    constexpr int FOLD_LDS = (2 * 80 * 264 + 80 * 168) * 2;  // 111360
    hipFuncSetAttribute((const void*)r2::fold_kernel,
                        hipFuncAttributeMaxDynamicSharedMemorySize, FOLD_LDS);
    r2::fold_kernel<<<250, 640, FOLD_LDS, stream>>>(tags, tag_parent, ws, out);
  }
}

// Round 13
// 378.055 us; speedup vs baseline: 1.2481x; 1.2447x over previous
//
#include <hip/hip_runtime.h>

// FasterGRUTree R12: R9 (best known, 393.9us) + one micro-fix: leaf phase-1
// staging batches ALL global loads before any LDS write (overlaps the 8 HBM
// round-trips that were serialized per (block,c) unit). Everything else is R9.
//  prep_kernel:  fp32 weights -> f16 fragment-ordered B operands + 16 bias tables.
//  leaf12_kernel: (313,8) blocks x 640 thr, BM=64: leaf GRU -> x-GEMM -> gi.
//  fold6_kernel: 250 blocks x 640 thr: 8-step fold (c=0 GEMM skipped) + node GRU.
// Fallback (ws too small): R2 split kernels (proven).

typedef _Float16 f16;
typedef _Float16 f16x4 __attribute__((ext_vector_type(4)));
typedef _Float16 f16x8 __attribute__((ext_vector_type(8)));
typedef float f32x4 __attribute__((ext_vector_type(4)));

namespace {

constexpr int NTREE = 20000;
constexpr int CCH   = 8;
constexpr int WORD  = 300;
constexpr int TAGD  = 50;
constexpr int MEMD  = 150;
constexpr int NBLK  = 250;   // fold blocks (80 trees each)
constexpr int LBLK  = 313;   // leaf blocks (64 trees each, last partial)

constexpr int KT_L = 11;     // leaf K tiles (352)
constexpr int KT_I = 8;      // x_child K tiles (256 = h|00|tag|tagp|0^4)
constexpr int KT_H = 5;      // hh K tiles (160)
constexpr int KT_N = 5;      // node K tiles (160)
constexpr int NTILE = 30;    // 3 gates x 10 j-tiles

constexpr size_t OFF_WL   = 0;
constexpr size_t OFF_WI   = OFF_WL + (size_t)KT_L * NTILE * 64 * 16;  // 337920
constexpr size_t OFF_WH   = OFF_WI + (size_t)KT_I * NTILE * 64 * 16;  // 583680
constexpr size_t OFF_WN   = OFF_WH + (size_t)KT_H * NTILE * 64 * 16;  // 737280
constexpr size_t OFF_BIAS = OFF_WN + (size_t)KT_N * NTILE * 64 * 16;  // 890880
constexpr size_t OFF_DATA = OFF_BIAS + 16 * 160 * 4;                  // 901120

// gi region: [c][tg 0..1249][unit = gate*10 + jt][lane][q] f16
constexpr size_t TG_BYTES = 15360;   // 30 units x 64 lanes x 8 B
constexpr size_t C_STRIDE = (size_t)1250 * TG_BYTES;                  // 19,200,000
constexpr size_t GI_BYTES = (size_t)CCH * C_STRIDE;                   // 153,600,000
constexpr size_t WS_R3    = OFF_DATA + GI_BYTES;
constexpr int    HW_S  = 152;
constexpr size_t WS_R2 = OFF_DATA + (size_t)CCH * NTREE * HW_S * 2;

// BIAS arrays (16 x 160 f32):
//  0 bL_r(ih+hh) 1 bL_z 2 bL_in 3 bL_hn | 4..7 child sums | 8..11 node
// 12 bC_ir 13 bC_iz 14 bC_hr 15 bC_hz

__device__ __forceinline__ float sigmoid_f(float x) {
  return 1.0f / (1.0f + __expf(-x));
}
__device__ __forceinline__ float tanh_f(float x) {
  float ax = fabsf(x);
  float e  = __expf(-2.0f * ax);
  float t  = (1.0f - e) / (1.0f + e);
  return copysignf(t, x);
}

// ---------------- prep ----------------
__global__ void prep_kernel(const float* __restrict__ w_ih_leaf,
                            const float* __restrict__ b_ih_leaf,
                            const float* __restrict__ b_hh_leaf,
                            const float* __restrict__ w_ih_child,
                            const float* __restrict__ w_hh_child,
                            const float* __restrict__ b_ih_child,
                            const float* __restrict__ b_hh_child,
                            const float* __restrict__ w_hh_node,
                            const float* __restrict__ b_ih_node,
                            const float* __restrict__ b_hh_node,
                            char* __restrict__ ws) {
  const int NWL = KT_L * NTILE * 64;  // 21120
  const int NWI = KT_I * NTILE * 64;  // 15360
  const int NWH = KT_H * NTILE * 64;  //  9600
  const int NWN = KT_N * NTILE * 64;  //  9600
  int t = blockIdx.x * blockDim.x + threadIdx.x;

  if (t < NWL) {  // w_ih_leaf, K=352
    int kt = t / (NTILE * 64), rem = t % (NTILE * 64);
    int nt = rem / 64, l = rem % 64;
    int gate = nt / 10, jt = nt % 10;
    int j = jt * 16 + (l & 15);
    bool valid = j < MEMD;
    int g = gate * MEMD + (valid ? j : 0);
    f16x8 v;
#pragma unroll
    for (int e = 0; e < 8; ++e) {
      int k = kt * 32 + ((l >> 4) * 8) + e;
      v[e] = (f16)((valid && k < WORD + TAGD) ? w_ih_leaf[g * (WORD + TAGD) + k] : 0.0f);
    }
    ((f16x8*)(ws + OFF_WL))[t] = v;
    return;
  }
  t -= NWL;
  if (t < NWI) {  // w_ih_child remapped: k<150 h | 152..201 tag | 202..251 tagp
    int kt = t / (NTILE * 64), rem = t % (NTILE * 64);
    int nt = rem / 64, l = rem % 64;
    int gate = nt / 10, jt = nt % 10;
    int j = jt * 16 + (l & 15);
    bool valid = j < MEMD;
    int g = gate * MEMD + (valid ? j : 0);
    f16x8 v;
#pragma unroll
    for (int e = 0; e < 8; ++e) {
      int k = kt * 32 + ((l >> 4) * 8) + e;
      int src = (k < 150) ? k : (k >= 152 && k < 252) ? (k - 2) : -1;
      v[e] = (f16)((valid && src >= 0) ? w_ih_child[g * 250 + src] : 0.0f);
    }
    ((f16x8*)(ws + OFF_WI))[t] = v;
    return;
  }
  t -= NWI;
  if (t < NWH) {  // w_hh_child, K=160
    int kt = t / (NTILE * 64), rem = t % (NTILE * 64);
    int nt = rem / 64, l = rem % 64;
    int gate = nt / 10, jt = nt % 10;
    int j = jt * 16 + (l & 15);
    bool valid = j < MEMD;
    int g = gate * MEMD + (valid ? j : 0);
    f16x8 v;
#pragma unroll
    for (int e = 0; e < 8; ++e) {
      int k = kt * 32 + ((l >> 4) * 8) + e;
      v[e] = (f16)((valid && k < MEMD) ? w_hh_child[g * MEMD + k] : 0.0f);
    }
    ((f16x8*)(ws + OFF_WH))[t] = v;
    return;
  }
  t -= NWH;
  if (t < NWN) {  // w_hh_node, K=160
    int kt = t / (NTILE * 64), rem = t % (NTILE * 64);
    int nt = rem / 64, l = rem % 64;
    int gate = nt / 10, jt = nt % 10;
    int j = jt * 16 + (l & 15);
    bool valid = j < MEMD;
    int g = gate * MEMD + (valid ? j : 0);
    f16x8 v;
#pragma unroll
    for (int e = 0; e < 8; ++e) {
      int k = kt * 32 + ((l >> 4) * 8) + e;
      v[e] = (f16)((valid && k < MEMD) ? w_hh_node[g * MEMD + k] : 0.0f);
    }
    ((f16x8*)(ws + OFF_WN))[t] = v;
    return;
  }
  t -= NWN;
  if (t < 16 * 160) {
    int arr = t / 160, j = t % 160;
    float v = 0.0f;
    if (j < MEMD) {
      switch (arr) {
        case 0:  v = b_ih_leaf[j] + b_hh_leaf[j]; break;
        case 1:  v = b_ih_leaf[MEMD + j] + b_hh_leaf[MEMD + j]; break;
        case 2:  v = b_ih_leaf[2 * MEMD + j]; break;
        case 3:  v = b_hh_leaf[2 * MEMD + j]; break;
        case 4:  v = b_ih_child[j] + b_hh_child[j]; break;
        case 5:  v = b_ih_child[MEMD + j] + b_hh_child[MEMD + j]; break;
        case 6:  v = b_ih_child[2 * MEMD + j]; break;
        case 7:  v = b_hh_child[2 * MEMD + j]; break;
        case 8:  v = b_ih_node[j] + b_hh_node[j]; break;
        case 9:  v = b_ih_node[MEMD + j] + b_hh_node[MEMD + j]; break;
        case 10: v = b_ih_node[2 * MEMD + j]; break;
        case 11: v = b_hh_node[2 * MEMD + j]; break;
        case 12: v = b_ih_child[j]; break;
        case 13: v = b_ih_child[MEMD + j]; break;
        case 14: v = b_hh_child[j]; break;
        case 15: v = b_hh_child[MEMD + j]; break;
      }
    }
    ((float*)(ws + OFF_BIAS))[arr * 160 + j] = v;
  }
}

// ---------------- leaf12: R9 leaf + batched phase-1 staging ----------------
__global__ __launch_bounds__(640, 1)
void leaf12_kernel(const float* __restrict__ embs,
                   const float* __restrict__ tags,
                   const float* __restrict__ tag_parent,
                   char* __restrict__ ws) {
  __shared__ f16 buf[64 * 360];   // 46080 B; xle stride 360 / xch stride 264 aliased
  f16* xle = buf;
  f16* xch = buf;

  const f16x8* WL   = (const f16x8*)(ws + OFF_WL);
  const f16x8* WI   = (const f16x8*)(ws + OFF_WI);
  const float* BIAS = (const float*)(ws + OFF_BIAS);

  const int tid = threadIdx.x, lane = tid & 63, w = tid >> 6;  // w: 0..9 = j-tile
  const int blk = blockIdx.x, c = blockIdx.y, t0 = blk * 64;
  const int arow = lane & 15, acol8 = (lane >> 4) * 8, qrow = (lane >> 4) * 4;
  const int j = w * 16 + arow;
  const bool jok = j < MEMD;

  // ---- phase 1: BATCHED issue of all staging loads, then write xle
  {
    float4 pe[8];
    float2 pt[2];
#pragma unroll
    for (int s = 0; s < 8; ++s) {
      int i = tid + 640 * s;
      if (i < 4800) {
        int r = i / 75, k4 = i - r * 75;
        int row = min(t0 + r, NTREE - 1);
        pe[s] = *(const float4*)(embs + ((size_t)row * CCH + c) * WORD + 4 * k4);
      }
    }
#pragma unroll
    for (int s = 0; s < 2; ++s) {   // 64*25 = 1600 slots, 2 strides of 640 cover 1280.. need 3
      int i = tid + 640 * s;
      if (i < 1600) {
        int r = i / 25, k2 = i - r * 25;
        int row = min(t0 + r, NTREE - 1);
        pt[s] = *(const float2*)(tags + ((size_t)row * CCH + c) * TAGD + 2 * k2);
      }
    }
    float2 pt2 = make_float2(0.0f, 0.0f);
    {
      int i = tid + 1280;
      if (i < 1600) {
        int r = i / 25, k2 = i - r * 25;
        int row = min(t0 + r, NTREE - 1);
        pt2 = *(const float2*)(tags + ((size_t)row * CCH + c) * TAGD + 2 * k2);
      }
    }
#pragma unroll
    for (int s = 0; s < 8; ++s) {
      int i = tid + 640 * s;
      if (i < 4800) {
        int r = i / 75, k4 = i - (i / 75) * 75;
        f16* p = xle + r * 360 + 4 * k4;
        p[0] = (f16)pe[s].x; p[1] = (f16)pe[s].y; p[2] = (f16)pe[s].z; p[3] = (f16)pe[s].w;
      }
    }
#pragma unroll
    for (int s = 0; s < 2; ++s) {
      int i = tid + 640 * s;
      if (i < 1600) {
        int r = i / 25, k2 = i - (i / 25) * 25;
        xle[r * 360 + 300 + 2 * k2]     = (f16)pt[s].x;
        xle[r * 360 + 300 + 2 * k2 + 1] = (f16)pt[s].y;
      }
    }
    {
      int i = tid + 1280;
      if (i < 1600) {
        int r = i / 25, k2 = i - (i / 25) * 25;
        xle[r * 360 + 300 + 2 * k2]     = (f16)pt2.x;
        xle[r * 360 + 300 + 2 * k2 + 1] = (f16)pt2.y;
      }
    }
  }
  if (tid < 64) {
    xle[tid * 360 + 350] = (f16)0.0f;
    xle[tid * 360 + 351] = (f16)0.0f;
  }
  __syncthreads();

  // ---- phase 2: leaf GEMM K=352
  f32x4 acc[3][4];
#pragma unroll
  for (int g = 0; g < 3; ++g)
#pragma unroll
    for (int m = 0; m < 4; ++m) acc[g][m] = 0.f;

  for (int kt = 0; kt < KT_L; ++kt) {
    f16x8 a0 = *(const f16x8*)(xle + kt * 32 + acol8 + (arow)      * 360);
    f16x8 a1 = *(const f16x8*)(xle + kt * 32 + acol8 + (16 + arow) * 360);
    f16x8 a2 = *(const f16x8*)(xle + kt * 32 + acol8 + (32 + arow) * 360);
    f16x8 a3 = *(const f16x8*)(xle + kt * 32 + acol8 + (48 + arow) * 360);
#pragma unroll
    for (int g = 0; g < 3; ++g) {
      f16x8 b = WL[(kt * NTILE + g * 10 + w) * 64 + lane];
      acc[g][0] = __builtin_amdgcn_mfma_f32_16x16x32_f16(a0, b, acc[g][0], 0, 0, 0);
      acc[g][1] = __builtin_amdgcn_mfma_f32_16x16x32_f16(a1, b, acc[g][1], 0, 0, 0);
      acc[g][2] = __builtin_amdgcn_mfma_f32_16x16x32_f16(a2, b, acc[g][2], 0, 0, 0);
      acc[g][3] = __builtin_amdgcn_mfma_f32_16x16x32_f16(a3, b, acc[g][3], 0, 0, 0);
    }
  }
  __syncthreads();  // all xle reads done; buf may now be rewritten as xch

  // ---- phase 3: build x_child in aliased buffer
  {
    const float bLr = BIAS[j], bLz = BIAS[160 + j];
    const float bLi = BIAS[320 + j], bLh = BIAS[480 + j];
#pragma unroll
    for (int m = 0; m < 4; ++m)
#pragma unroll
      for (int q = 0; q < 4; ++q) {
        int row = 16 * m + qrow + q;
        float rg = sigmoid_f(acc[0][m][q] + bLr);
        float zg = sigmoid_f(acc[1][m][q] + bLz);
        float ng = tanh_f(acc[2][m][q] + bLi + rg * bLh);
        if (jok) xch[row * 264 + j] = (f16)((1.0f - zg) * ng);  // h0 = 0
      }
  }
  for (int i = tid; i < 64 * 25; i += 640) {
    int r = i / 25, k2 = i - r * 25;
    int row = min(t0 + r, NTREE - 1);
    float2 v = *(const float2*)(tags + ((size_t)row * CCH + c) * TAGD + 2 * k2);
    xch[r * 264 + 152 + 2 * k2] = (f16)v.x;
    xch[r * 264 + 153 + 2 * k2] = (f16)v.y;
  }
  for (int i = tid; i < 64 * 25; i += 640) {
    int r = i / 25, k2 = i - r * 25;
    int row = min(t0 + r, NTREE - 1);
    float2 v = *(const float2*)(tag_parent + (size_t)row * TAGD + 2 * k2);
    xch[r * 264 + 202 + 2 * k2] = (f16)v.x;
    xch[r * 264 + 203 + 2 * k2] = (f16)v.y;
  }
  for (int i = tid; i < 64 * 6; i += 640) {
    int r = i / 6, k = i - r * 6;
    int col = (k < 2) ? (150 + k) : (250 + k);  // 150,151,252..255
    xch[r * 264 + col] = (f16)0.0f;
  }
  __syncthreads();

  // ---- phase 4: x-GEMM K=256
#pragma unroll
  for (int g = 0; g < 3; ++g)
#pragma unroll
    for (int m = 0; m < 4; ++m) acc[g][m] = 0.f;

  for (int kt = 0; kt < KT_I; ++kt) {
    f16x8 a0 = *(const f16x8*)(xch + kt * 32 + acol8 + (arow)      * 264);
    f16x8 a1 = *(const f16x8*)(xch + kt * 32 + acol8 + (16 + arow) * 264);
    f16x8 a2 = *(const f16x8*)(xch + kt * 32 + acol8 + (32 + arow) * 264);
    f16x8 a3 = *(const f16x8*)(xch + kt * 32 + acol8 + (48 + arow) * 264);
#pragma unroll
    for (int g = 0; g < 3; ++g) {
      f16x8 b = WI[(kt * NTILE + g * 10 + w) * 64 + lane];
      acc[g][0] = __builtin_amdgcn_mfma_f32_16x16x32_f16(a0, b, acc[g][0], 0, 0, 0);
      acc[g][1] = __builtin_amdgcn_mfma_f32_16x16x32_f16(a1, b, acc[g][1], 0, 0, 0);
      acc[g][2] = __builtin_amdgcn_mfma_f32_16x16x32_f16(a2, b, acc[g][2], 0, 0, 0);
      acc[g][3] = __builtin_amdgcn_mfma_f32_16x16x32_f16(a3, b, acc[g][3], 0, 0, 0);
    }
  }

  // ---- phase 5: bake b_ih_child, store fragment-ordered gi (tail-guarded)
  {
    const float bi[3] = {BIAS[12 * 160 + j], BIAS[13 * 160 + j], BIAS[6 * 160 + j]};
#pragma unroll
    for (int m = 0; m < 4; ++m) {
      if (t0 + 16 * m < NTREE) {
        int tg = blk * 4 + m;
        char* base = ws + OFF_DATA + (size_t)c * C_STRIDE + (size_t)tg * TG_BYTES +
                     (size_t)lane * 8;
#pragma unroll
        for (int g = 0; g < 3; ++g) {
          f16x4 v;
#pragma unroll
          for (int q = 0; q < 4; ++q) v[q] = (f16)(acc[g][m][q] + bi[g]);
          *(f16x4*)(base + (size_t)(g * 10 + w) * 512) = v;
        }
      }
    }
  }
}

// ---------------- fold6 (R9): 8-step serial fold + node, all W_hh hoisted ----------------
__global__ __launch_bounds__(640, 1)
void fold6_kernel(const char* __restrict__ ws,
                  float* __restrict__ out) {
  __shared__ f16 hls[80 * 168];   // 26880 B

  const f16x8* WH   = (const f16x8*)(ws + OFF_WH);
  const f16x8* WN   = (const f16x8*)(ws + OFF_WN);
  const float* BIAS = (const float*)(ws + OFF_BIAS);

  const int tid = threadIdx.x, lane = tid & 63, w = tid >> 6;  // w: 0..9
  const int blk = blockIdx.x, t0 = blk * 80;
  const int arow = lane & 15, acol8 = (lane >> 4) * 8, qrow = (lane >> 4) * 4;
  const int j = w * 16 + arow;
  const bool jok = j < MEMD;

  const float bhr = BIAS[14 * 160 + j], bhz = BIAS[15 * 160 + j], bhn = BIAS[7 * 160 + j];
  const float bNr = BIAS[8 * 160 + j],  bNz = BIAS[9 * 160 + j];
  const float bNi = BIAS[10 * 160 + j], bNh = BIAS[11 * 160 + j];

  for (int i = tid; i < 80 * 18; i += 640) {
    int r = i / 18;
    hls[r * 168 + 150 + (i - r * 18)] = (f16)0.0f;
  }

  f16x8 whr[5], whz[5], whn[5];
#pragma unroll
  for (int kt = 0; kt < KT_H; ++kt) {
    whr[kt] = WH[(kt * NTILE + w) * 64 + lane];
    whz[kt] = WH[(kt * NTILE + 10 + w) * 64 + lane];
    whn[kt] = WH[(kt * NTILE + 20 + w) * 64 + lane];
  }

  const char* gbase = ws + OFF_DATA + (size_t)(blk * 5) * TG_BYTES +
                      (size_t)w * 512 + (size_t)lane * 8;

  f32x4 hp[5];
#pragma unroll
  for (int m = 0; m < 5; ++m) hp[m] = 0.f;

#pragma unroll
  for (int c = 0; c < CCH; ++c) {
    f16x4 gbuf[15];
#pragma unroll
    for (int m = 0; m < 5; ++m)
#pragma unroll
      for (int g = 0; g < 3; ++g)
        gbuf[m * 3 + g] = *(const f16x4*)(gbase + (size_t)c * C_STRIDE +
                                          (size_t)m * TG_BYTES + (size_t)g * 5120);

    f32x4 aR[5], aZ[5], aNh[5];
#pragma unroll
    for (int m = 0; m < 5; ++m) { aR[m] = 0.f; aZ[m] = 0.f; aNh[m] = 0.f; }

    if (c != 0) {  // c=0: h=0 -> gh contribution zero; skip GEMM + barrier
#pragma unroll
      for (int kt = 0; kt < KT_H; ++kt) {
        const f16* ab = hls + kt * 32 + acol8;
#pragma unroll
        for (int m = 0; m < 5; ++m) {
          f16x8 a = *(const f16x8*)(ab + (16 * m + arow) * 168);
          aR[m]  = __builtin_amdgcn_mfma_f32_16x16x32_f16(a, whr[kt], aR[m], 0, 0, 0);
          aZ[m]  = __builtin_amdgcn_mfma_f32_16x16x32_f16(a, whz[kt], aZ[m], 0, 0, 0);
          aNh[m] = __builtin_amdgcn_mfma_f32_16x16x32_f16(a, whn[kt], aNh[m], 0, 0, 0);
        }
      }
      __syncthreads();  // B1
    }

#pragma unroll
    for (int m = 0; m < 5; ++m)
#pragma unroll
      for (int q = 0; q < 4; ++q) {
        int row = 16 * m + qrow + q;
        float rg = sigmoid_f((float)gbuf[m * 3 + 0][q] + aR[m][q] + bhr);
        float zg = sigmoid_f((float)gbuf[m * 3 + 1][q] + aZ[m][q] + bhz);
        float ng = tanh_f((float)gbuf[m * 3 + 2][q] + rg * (aNh[m][q] + bhn));
        float h  = (1.0f - zg) * ng + zg * hp[m][q];
        hp[m][q] = h;
        if (jok) hls[row * 168 + j] = (f16)h;
      }
    __syncthreads();  // B2
  }

  // node GRU
  f32x4 aR[5], aZ[5], aNh[5];
#pragma unroll
  for (int m = 0; m < 5; ++m) { aR[m] = 0.f; aZ[m] = 0.f; aNh[m] = 0.f; }
  for (int kt = 0; kt < KT_N; ++kt) {
    f16x8 br = WN[(kt * NTILE + w) * 64 + lane];
    f16x8 bz = WN[(kt * NTILE + 10 + w) * 64 + lane];
    f16x8 bn = WN[(kt * NTILE + 20 + w) * 64 + lane];
    const f16* ab = hls + kt * 32 + acol8;
#pragma unroll
    for (int m = 0; m < 5; ++m) {
      f16x8 a = *(const f16x8*)(ab + (16 * m + arow) * 168);
      aR[m]  = __builtin_amdgcn_mfma_f32_16x16x32_f16(a, br, aR[m], 0, 0, 0);
      aZ[m]  = __builtin_amdgcn_mfma_f32_16x16x32_f16(a, bz, aZ[m], 0, 0, 0);
      aNh[m] = __builtin_amdgcn_mfma_f32_16x16x32_f16(a, bn, aNh[m], 0, 0, 0);
    }
  }
#pragma unroll
  for (int m = 0; m < 5; ++m)
#pragma unroll
    for (int q = 0; q < 4; ++q) {
      int row = 16 * m + qrow + q;
      float rg = sigmoid_f(aR[m][q] + bNr);
      float zg = sigmoid_f(aZ[m][q] + bNz);
      float ng = tanh_f(bNi + rg * (aNh[m][q] + bNh));
      float o  = (1.0f - zg) * ng + zg * hp[m][q];
      if (jok) out[(size_t)(t0 + row) * MEMD + j] = o;
    }
}

// ================= R2 fallback (proven) =================
namespace r2 {

__global__ __launch_bounds__(640)
void leaf_kernel(const float* __restrict__ embs,
                 const float* __restrict__ tags,
                 char* __restrict__ ws) {
  __shared__ f16 xle[80 * 360];
  const f16x8* WL   = (const f16x8*)(ws + OFF_WL);
  const float* BIAS = (const float*)(ws + OFF_BIAS);
  f16* hws = (f16*)(ws + OFF_DATA);

  const int tid = threadIdx.x, lane = tid & 63, w = tid >> 6;
  const int c = blockIdx.y, t0 = blockIdx.x * 80;
  const int arow = lane & 15, acol8 = (lane >> 4) * 8, qrow = (lane >> 4) * 4;
  const int j = w * 16 + (lane & 15);

  for (int i = tid; i < 80 * 150; i += 640) {
    int r = i / 150, k2 = i - r * 150;
    float2 v = *(const float2*)(embs + ((size_t)(t0 + r) * CCH + c) * WORD + 2 * k2);
    xle[r * 360 + 2 * k2]     = (f16)v.x;
    xle[r * 360 + 2 * k2 + 1] = (f16)v.y;
  }
  for (int i = tid; i < 80 * 25; i += 640) {
    int r = i / 25, k2 = i - r * 25;
    float2 v = *(const float2*)(tags + ((size_t)(t0 + r) * CCH + c) * TAGD + 2 * k2);
    xle[r * 360 + 300 + 2 * k2]     = (f16)v.x;
    xle[r * 360 + 300 + 2 * k2 + 1] = (f16)v.y;
  }
  for (int i = tid; i < 80; i += 640) {
    xle[i * 360 + 350] = (f16)0.0f;
    xle[i * 360 + 351] = (f16)0.0f;
  }
  __syncthreads();

  f32x4 aR[5], aZ[5], aN[5];
#pragma unroll
  for (int m = 0; m < 5; ++m) { aR[m] = 0.f; aZ[m] = 0.f; aN[m] = 0.f; }
  for (int kt = 0; kt < KT_L; ++kt) {
    f16x8 br = WL[(kt * NTILE + w) * 64 + lane];
    f16x8 bz = WL[(kt * NTILE + 10 + w) * 64 + lane];
    f16x8 bn = WL[(kt * NTILE + 20 + w) * 64 + lane];
    const f16* ab = xle + kt * 32 + acol8;
#pragma unroll
    for (int m = 0; m < 5; ++m) {
      f16x8 a = *(const f16x8*)(ab + (16 * m + arow) * 360);
      aR[m] = __builtin_amdgcn_mfma_f32_16x16x32_f16(a, br, aR[m], 0, 0, 0);
      aZ[m] = __builtin_amdgcn_mfma_f32_16x16x32_f16(a, bz, aZ[m], 0, 0, 0);
      aN[m] = __builtin_amdgcn_mfma_f32_16x16x32_f16(a, bn, aN[m], 0, 0, 0);
    }
  }
  const float bLr = BIAS[j], bLz = BIAS[160 + j], bLi = BIAS[320 + j], bLh = BIAS[480 + j];
#pragma unroll
  for (int m = 0; m < 5; ++m) {
#pragma unroll
    for (int q = 0; q < 4; ++q) {
      int row = 16 * m + qrow + q;
      float rg = sigmoid_f(aR[m][q] + bLr);
      float zg = sigmoid_f(aZ[m][q] + bLz);
      float ng = tanh_f(aN[m][q] + bLi + rg * bLh);
      float h  = (1.0f - zg) * ng;
      if (j < HW_S)
        hws[((size_t)c * NTREE + t0 + row) * HW_S + j] = (f16)(j < MEMD ? h : 0.0f);
    }
  }
}

__global__ __launch_bounds__(640)
void fold_kernel(const float* __restrict__ tags,
                 const float* __restrict__ tag_parent,
                 const char* __restrict__ ws,
                 float* __restrict__ out) {
  extern __shared__ char fsm[];
  f16* xch0 = (f16*)fsm;
  f16* xch1 = xch0 + 80 * 264;
  f16* hls  = xch1 + 80 * 264;

  const f16x8* WI   = (const f16x8*)(ws + OFF_WI);
  const f16x8* WH   = (const f16x8*)(ws + OFF_WH);
  const f16x8* WN   = (const f16x8*)(ws + OFF_WN);
  const float* BIAS = (const float*)(ws + OFF_BIAS);
  const f16*   hws  = (const f16*)(ws + OFF_DATA);

  const int tid = threadIdx.x, lane = tid & 63, w = tid >> 6;
  const int t0 = blockIdx.x * 80;
  const int arow = lane & 15, acol8 = (lane >> 4) * 8, qrow = (lane >> 4) * 4;
  const int j = w * 16 + (lane & 15);
  const bool jok = j < MEMD;

  const float bCr = BIAS[4 * 160 + j], bCz = BIAS[5 * 160 + j];
  const float bCi = BIAS[6 * 160 + j], bCh = BIAS[7 * 160 + j];
  const float bNr = BIAS[8 * 160 + j], bNz = BIAS[9 * 160 + j];
  const float bNi = BIAS[10 * 160 + j], bNh = BIAS[11 * 160 + j];

  for (int i = tid; i < 1680; i += 640) ((int4*)hls)[i] = make_int4(0, 0, 0, 0);
  for (int i = tid; i < 80 * 25; i += 640) {
    int r = i / 25, k2 = i - r * 25;
    float2 v = *(const float2*)(tag_parent + (size_t)(t0 + r) * TAGD + 2 * k2);
    f16 a = (f16)v.x, b = (f16)v.y;
    xch0[r * 264 + 202 + 2 * k2] = a; xch0[r * 264 + 203 + 2 * k2] = b;
    xch1[r * 264 + 202 + 2 * k2] = a; xch1[r * 264 + 203 + 2 * k2] = b;
  }
  for (int i = tid; i < 80 * 4; i += 640) {
    int r = i >> 2, k = i & 3;
    xch0[r * 264 + 252 + k] = (f16)0.0f;
    xch1[r * 264 + 252 + k] = (f16)0.0f;
  }
#pragma unroll
  for (int s = 0; s < 3; ++s) {
    int i = tid + 640 * s;
    if (i < 1520) {
      int r = i / 19, q = i - r * 19;
      *(f16x8*)(xch0 + r * 264 + 8 * q) =
          *(const f16x8*)(hws + ((size_t)(t0 + r)) * HW_S + 8 * q);
    }
  }
#pragma unroll
  for (int s = 0; s < 4; ++s) {
    int i = tid + 640 * s;
    if (i < 2000) {
      int r = i / 25, k2 = i - r * 25;
      float2 v = *(const float2*)(tags + ((size_t)(t0 + r) * CCH) * TAGD + 2 * k2);
      xch0[r * 264 + 152 + 2 * k2] = (f16)v.x;
      xch0[r * 264 + 153 + 2 * k2] = (f16)v.y;
    }
  }
  __syncthreads();

  f32x4 hp[5];
#pragma unroll
  for (int m = 0; m < 5; ++m) hp[m] = 0.f;

  f16* xc = xch0;
  f16* xa = xch1;

  for (int c = 0; c < CCH; ++c) {
    f16x8 ph[3];
    float2 pt[4];
    if (c < 7) {
#pragma unroll
      for (int s = 0; s < 3; ++s) {
        int i = tid + 640 * s;
        if (i < 1520) {
          int r = i / 19, q = i - r * 19;
          ph[s] = *(const f16x8*)(hws + ((size_t)(c + 1) * NTREE + t0 + r) * HW_S + 8 * q);
        }
      }
#pragma unroll
      for (int s = 0; s < 4; ++s) {
        int i = tid + 640 * s;
        if (i < 2000) {
          int r = i / 25, k2 = i - r * 25;
          pt[s] = *(const float2*)(tags + ((size_t)(t0 + r) * CCH + (c + 1)) * TAGD + 2 * k2);
        }
      }
    }

    f32x4 aR[5], aZ[5], aNi[5], aNh[5];
#pragma unroll
    for (int m = 0; m < 5; ++m) { aR[m] = 0.f; aZ[m] = 0.f; aNi[m] = 0.f; aNh[m] = 0.f; }
    for (int kt = 0; kt < KT_I; ++kt) {
      f16x8 br = WI[(kt * NTILE + w) * 64 + lane];
      f16x8 bz = WI[(kt * NTILE + 10 + w) * 64 + lane];
      f16x8 bn = WI[(kt * NTILE + 20 + w) * 64 + lane];
      const f16* ab = xc + kt * 32 + acol8;
#pragma unroll
      for (int m = 0; m < 5; ++m) {
        f16x8 a = *(const f16x8*)(ab + (16 * m + arow) * 264);
        aR[m]  = __builtin_amdgcn_mfma_f32_16x16x32_f16(a, br, aR[m], 0, 0, 0);
        aZ[m]  = __builtin_amdgcn_mfma_f32_16x16x32_f16(a, bz, aZ[m], 0, 0, 0);
        aNi[m] = __builtin_amdgcn_mfma_f32_16x16x32_f16(a, bn, aNi[m], 0, 0, 0);
      }
    }
    for (int kt = 0; kt < KT_H; ++kt) {
      f16x8 br = WH[(kt * NTILE + w) * 64 + lane];
      f16x8 bz = WH[(kt * NTILE + 10 + w) * 64 + lane];
      f16x8 bn = WH[(kt * NTILE + 20 + w) * 64 + lane];
      const f16* ab = hls + kt * 32 + acol8;
#pragma unroll
      for (int m = 0; m < 5; ++m) {
        f16x8 a = *(const f16x8*)(ab + (16 * m + arow) * 168);
        aR[m]  = __builtin_amdgcn_mfma_f32_16x16x32_f16(a, br, aR[m], 0, 0, 0);
        aZ[m]  = __builtin_amdgcn_mfma_f32_16x16x32_f16(a, bz, aZ[m], 0, 0, 0);
        aNh[m] = __builtin_amdgcn_mfma_f32_16x16x32_f16(a, bn, aNh[m], 0, 0, 0);
      }
    }
    __syncthreads();

    if (c < 7) {
#pragma unroll
      for (int s = 0; s < 3; ++s) {
        int i = tid + 640 * s;
        if (i < 1520) {
          int r = i / 19, q = i - r * 19;
          *(f16x8*)(xa + r * 264 + 8 * q) = ph[s];
        }
      }
#pragma unroll
      for (int s = 0; s < 4; ++s) {
        int i = tid + 640 * s;
        if (i < 2000) {
          int r = i / 25, k2 = i - r * 25;
          xa[r * 264 + 152 + 2 * k2] = (f16)pt[s].x;
          xa[r * 264 + 153 + 2 * k2] = (f16)pt[s].y;
        }
      }
    }

#pragma unroll
    for (int m = 0; m < 5; ++m) {
#pragma unroll
      for (int q = 0; q < 4; ++q) {
        int row = 16 * m + qrow + q;
        float rg = sigmoid_f(aR[m][q] + bCr);
        float zg = sigmoid_f(aZ[m][q] + bCz);
        float ng = tanh_f(aNi[m][q] + bCi + rg * (aNh[m][q] + bCh));
        float h  = (1.0f - zg) * ng + zg * hp[m][q];
        hp[m][q] = h;
        if (jok) hls[row * 168 + j] = (f16)h;
      }
    }
    __syncthreads();
    f16* tsw = xc; xc = xa; xa = tsw;
  }

  f32x4 aR[5], aZ[5], aNh[5];
#pragma unroll
  for (int m = 0; m < 5; ++m) { aR[m] = 0.f; aZ[m] = 0.f; aNh[m] = 0.f; }
  for (int kt = 0; kt < KT_N; ++kt) {
    f16x8 br = WN[(kt * NTILE + w) * 64 + lane];
    f16x8 bz = WN[(kt * NTILE + 10 + w) * 64 + lane];
    f16x8 bn = WN[(kt * NTILE + 20 + w) * 64 + lane];
    const f16* ab = hls + kt * 32 + acol8;
#pragma unroll
    for (int m = 0; m < 5; ++m) {
      f16x8 a = *(const f16x8*)(ab + (16 * m + arow) * 168);
      aR[m]  = __builtin_amdgcn_mfma_f32_16x16x32_f16(a, br, aR[m], 0, 0, 0);
      aZ[m]  = __builtin_amdgcn_mfma_f32_16x16x32_f16(a, bz, aZ[m], 0, 0, 0);
      aNh[m] = __builtin_amdgcn_mfma_f32_16x16x32_f16(a, bn, aNh[m], 0, 0, 0);
    }
  }
#pragma unroll
  for (int m = 0; m < 5; ++m) {
#pragma unroll
    for (int q = 0; q < 4; ++q) {
      int row = 16 * m + qrow + q;
      float rg = sigmoid_f(aR[m][q] + bNr);
      float zg = sigmoid_f(aZ[m][q] + bNz);
      float ng = tanh_f(bNi + rg * (aNh[m][q] + bNh));
      float o  = (1.0f - zg) * ng + zg * hp[m][q];
      if (jok) out[(size_t)(t0 + row) * MEMD + j] = o;
    }
  }
}

}  // namespace r2

}  // namespace

extern "C" void kernel_launch(void* const* d_in, const int* in_sizes, int n_in,
                              void* d_out, int out_size, void* d_ws, size_t ws_size,
                              hipStream_t stream) {
  const float* embs       = (const float*)d_in[0];
  const float* tags       = (const float*)d_in[1];
  const float* tag_parent = (const float*)d_in[2];
  const float* w_ih_leaf  = (const float*)d_in[3];
  // d_in[4] w_hh_leaf unused (h0 = 0)
  const float* b_ih_leaf  = (const float*)d_in[5];
  const float* b_hh_leaf  = (const float*)d_in[6];
  const float* w_ih_child = (const float*)d_in[7];
  const float* w_hh_child = (const float*)d_in[8];
  const float* b_ih_child = (const float*)d_in[9];
  const float* b_hh_child = (const float*)d_in[10];
  // d_in[11] w_ih_node unused (x = 0)
  const float* w_hh_node  = (const float*)d_in[12];
  const float* b_ih_node  = (const float*)d_in[13];
  const float* b_hh_node  = (const float*)d_in[14];
  float* out = (float*)d_out;
  char*  ws  = (char*)d_ws;

  prep_kernel<<<228, 256, 0, stream>>>(w_ih_leaf, b_ih_leaf, b_hh_leaf,
                                       w_ih_child, w_hh_child, b_ih_child, b_hh_child,
                                       w_hh_node, b_ih_node, b_hh_node, ws);

  if (ws_size >= WS_R3) {
    leaf12_kernel<<<dim3(LBLK, CCH), 640, 0, stream>>>(embs, tags, tag_parent, ws);
    fold6_kernel<<<NBLK, 640, 0, stream>>>(ws, out);
  } else {
    r2::leaf_kernel<<<dim3(250, CCH), 640, 0, stream>>>(embs, tags, ws);
    constexpr int FOLD_LDS = (2 * 80 * 264 + 80 * 168) * 2;  // 111360
    hipFuncSetAttribute((const void*)r2::fold_kernel,
                        hipFuncAttributeMaxDynamicSharedMemorySize, FOLD_LDS);
    r2::fold_kernel<<<250, 640, FOLD_LDS, stream>>>(tags, tag_parent, ws, out);
  }
}

// Round 14
// 368.937 us; speedup vs baseline: 1.2789x; 1.0247x over previous
//
#include <hip/hip_runtime.h>

// FasterGRUTree R13: R12 (best known, 378.1us) + fold h double-buffer
// (one barrier per step instead of two; correctness proven in R11 run).
//  prep_kernel:  fp32 weights -> f16 fragment-ordered B operands + 16 bias tables.
//  leaf12_kernel: (313,8) blocks x 640 thr, BM=64, batched phase-1 staging.
//  fold13_kernel: 250 blocks x 640 thr: 8-step fold, h dbuf, 1 barrier/step.
// Fallback (ws too small): R2 split kernels (proven).

typedef _Float16 f16;
typedef _Float16 f16x4 __attribute__((ext_vector_type(4)));
typedef _Float16 f16x8 __attribute__((ext_vector_type(8)));
typedef float f32x4 __attribute__((ext_vector_type(4)));

namespace {

constexpr int NTREE = 20000;
constexpr int CCH   = 8;
constexpr int WORD  = 300;
constexpr int TAGD  = 50;
constexpr int MEMD  = 150;
constexpr int NBLK  = 250;   // fold blocks (80 trees each)
constexpr int LBLK  = 313;   // leaf blocks (64 trees each, last partial)

constexpr int KT_L = 11;     // leaf K tiles (352)
constexpr int KT_I = 8;      // x_child K tiles (256 = h|00|tag|tagp|0^4)
constexpr int KT_H = 5;      // hh K tiles (160)
constexpr int KT_N = 5;      // node K tiles (160)
constexpr int NTILE = 30;    // 3 gates x 10 j-tiles

constexpr size_t OFF_WL   = 0;
constexpr size_t OFF_WI   = OFF_WL + (size_t)KT_L * NTILE * 64 * 16;  // 337920
constexpr size_t OFF_WH   = OFF_WI + (size_t)KT_I * NTILE * 64 * 16;  // 583680
constexpr size_t OFF_WN   = OFF_WH + (size_t)KT_H * NTILE * 64 * 16;  // 737280
constexpr size_t OFF_BIAS = OFF_WN + (size_t)KT_N * NTILE * 64 * 16;  // 890880
constexpr size_t OFF_DATA = OFF_BIAS + 16 * 160 * 4;                  // 901120

// gi region: [c][tg 0..1249][unit = gate*10 + jt][lane][q] f16
constexpr size_t TG_BYTES = 15360;   // 30 units x 64 lanes x 8 B
constexpr size_t C_STRIDE = (size_t)1250 * TG_BYTES;                  // 19,200,000
constexpr size_t GI_BYTES = (size_t)CCH * C_STRIDE;                   // 153,600,000
constexpr size_t WS_R3    = OFF_DATA + GI_BYTES;
constexpr int    HW_S  = 152;
constexpr size_t WS_R2 = OFF_DATA + (size_t)CCH * NTREE * HW_S * 2;

// BIAS arrays (16 x 160 f32):
//  0 bL_r(ih+hh) 1 bL_z 2 bL_in 3 bL_hn | 4..7 child sums | 8..11 node
// 12 bC_ir 13 bC_iz 14 bC_hr 15 bC_hz

__device__ __forceinline__ float sigmoid_f(float x) {
  return 1.0f / (1.0f + __expf(-x));
}
__device__ __forceinline__ float tanh_f(float x) {
  float ax = fabsf(x);
  float e  = __expf(-2.0f * ax);
  float t  = (1.0f - e) / (1.0f + e);
  return copysignf(t, x);
}

// ---------------- prep ----------------
__global__ void prep_kernel(const float* __restrict__ w_ih_leaf,
                            const float* __restrict__ b_ih_leaf,
                            const float* __restrict__ b_hh_leaf,
                            const float* __restrict__ w_ih_child,
                            const float* __restrict__ w_hh_child,
                            const float* __restrict__ b_ih_child,
                            const float* __restrict__ b_hh_child,
                            const float* __restrict__ w_hh_node,
                            const float* __restrict__ b_ih_node,
                            const float* __restrict__ b_hh_node,
                            char* __restrict__ ws) {
  const int NWL = KT_L * NTILE * 64;  // 21120
  const int NWI = KT_I * NTILE * 64;  // 15360
  const int NWH = KT_H * NTILE * 64;  //  9600
  const int NWN = KT_N * NTILE * 64;  //  9600
  int t = blockIdx.x * blockDim.x + threadIdx.x;

  if (t < NWL) {  // w_ih_leaf, K=352
    int kt = t / (NTILE * 64), rem = t % (NTILE * 64);
    int nt = rem / 64, l = rem % 64;
    int gate = nt / 10, jt = nt % 10;
    int j = jt * 16 + (l & 15);
    bool valid = j < MEMD;
    int g = gate * MEMD + (valid ? j : 0);
    f16x8 v;
#pragma unroll
    for (int e = 0; e < 8; ++e) {
      int k = kt * 32 + ((l >> 4) * 8) + e;
      v[e] = (f16)((valid && k < WORD + TAGD) ? w_ih_leaf[g * (WORD + TAGD) + k] : 0.0f);
    }
    ((f16x8*)(ws + OFF_WL))[t] = v;
    return;
  }
  t -= NWL;
  if (t < NWI) {  // w_ih_child remapped: k<150 h | 152..201 tag | 202..251 tagp
    int kt = t / (NTILE * 64), rem = t % (NTILE * 64);
    int nt = rem / 64, l = rem % 64;
    int gate = nt / 10, jt = nt % 10;
    int j = jt * 16 + (l & 15);
    bool valid = j < MEMD;
    int g = gate * MEMD + (valid ? j : 0);
    f16x8 v;
#pragma unroll
    for (int e = 0; e < 8; ++e) {
      int k = kt * 32 + ((l >> 4) * 8) + e;
      int src = (k < 150) ? k : (k >= 152 && k < 252) ? (k - 2) : -1;
      v[e] = (f16)((valid && src >= 0) ? w_ih_child[g * 250 + src] : 0.0f);
    }
    ((f16x8*)(ws + OFF_WI))[t] = v;
    return;
  }
  t -= NWI;
  if (t < NWH) {  // w_hh_child, K=160
    int kt = t / (NTILE * 64), rem = t % (NTILE * 64);
    int nt = rem / 64, l = rem % 64;
    int gate = nt / 10, jt = nt % 10;
    int j = jt * 16 + (l & 15);
    bool valid = j < MEMD;
    int g = gate * MEMD + (valid ? j : 0);
    f16x8 v;
#pragma unroll
    for (int e = 0; e < 8; ++e) {
      int k = kt * 32 + ((l >> 4) * 8) + e;
      v[e] = (f16)((valid && k < MEMD) ? w_hh_child[g * MEMD + k] : 0.0f);
    }
    ((f16x8*)(ws + OFF_WH))[t] = v;
    return;
  }
  t -= NWH;
  if (t < NWN) {  // w_hh_node, K=160
    int kt = t / (NTILE * 64), rem = t % (NTILE * 64);
    int nt = rem / 64, l = rem % 64;
    int gate = nt / 10, jt = nt % 10;
    int j = jt * 16 + (l & 15);
    bool valid = j < MEMD;
    int g = gate * MEMD + (valid ? j : 0);
    f16x8 v;
#pragma unroll
    for (int e = 0; e < 8; ++e) {
      int k = kt * 32 + ((l >> 4) * 8) + e;
      v[e] = (f16)((valid && k < MEMD) ? w_hh_node[g * MEMD + k] : 0.0f);
    }
    ((f16x8*)(ws + OFF_WN))[t] = v;
    return;
  }
  t -= NWN;
  if (t < 16 * 160) {
    int arr = t / 160, j = t % 160;
    float v = 0.0f;
    if (j < MEMD) {
      switch (arr) {
        case 0:  v = b_ih_leaf[j] + b_hh_leaf[j]; break;
        case 1:  v = b_ih_leaf[MEMD + j] + b_hh_leaf[MEMD + j]; break;
        case 2:  v = b_ih_leaf[2 * MEMD + j]; break;
        case 3:  v = b_hh_leaf[2 * MEMD + j]; break;
        case 4:  v = b_ih_child[j] + b_hh_child[j]; break;
        case 5:  v = b_ih_child[MEMD + j] + b_hh_child[MEMD + j]; break;
        case 6:  v = b_ih_child[2 * MEMD + j]; break;
        case 7:  v = b_hh_child[2 * MEMD + j]; break;
        case 8:  v = b_ih_node[j] + b_hh_node[j]; break;
        case 9:  v = b_ih_node[MEMD + j] + b_hh_node[MEMD + j]; break;
        case 10: v = b_ih_node[2 * MEMD + j]; break;
        case 11: v = b_hh_node[2 * MEMD + j]; break;
        case 12: v = b_ih_child[j]; break;
        case 13: v = b_ih_child[MEMD + j]; break;
        case 14: v = b_hh_child[j]; break;
        case 15: v = b_hh_child[MEMD + j]; break;
      }
    }
    ((float*)(ws + OFF_BIAS))[arr * 160 + j] = v;
  }
}

// ---------------- leaf12 (R12): batched phase-1 staging ----------------
__global__ __launch_bounds__(640, 1)
void leaf12_kernel(const float* __restrict__ embs,
                   const float* __restrict__ tags,
                   const float* __restrict__ tag_parent,
                   char* __restrict__ ws) {
  __shared__ f16 buf[64 * 360];   // 46080 B; xle stride 360 / xch stride 264 aliased
  f16* xle = buf;
  f16* xch = buf;

  const f16x8* WL   = (const f16x8*)(ws + OFF_WL);
  const f16x8* WI   = (const f16x8*)(ws + OFF_WI);
  const float* BIAS = (const float*)(ws + OFF_BIAS);

  const int tid = threadIdx.x, lane = tid & 63, w = tid >> 6;  // w: 0..9 = j-tile
  const int blk = blockIdx.x, c = blockIdx.y, t0 = blk * 64;
  const int arow = lane & 15, acol8 = (lane >> 4) * 8, qrow = (lane >> 4) * 4;
  const int j = w * 16 + arow;
  const bool jok = j < MEMD;

  // ---- phase 1: BATCHED issue of all staging loads, then write xle
  {
    float4 pe[8];
    float2 pt[2];
#pragma unroll
    for (int s = 0; s < 8; ++s) {
      int i = tid + 640 * s;
      if (i < 4800) {
        int r = i / 75, k4 = i - r * 75;
        int row = min(t0 + r, NTREE - 1);
        pe[s] = *(const float4*)(embs + ((size_t)row * CCH + c) * WORD + 4 * k4);
      }
    }
#pragma unroll
    for (int s = 0; s < 2; ++s) {
      int i = tid + 640 * s;
      if (i < 1600) {
        int r = i / 25, k2 = i - r * 25;
        int row = min(t0 + r, NTREE - 1);
        pt[s] = *(const float2*)(tags + ((size_t)row * CCH + c) * TAGD + 2 * k2);
      }
    }
    float2 pt2 = make_float2(0.0f, 0.0f);
    {
      int i = tid + 1280;
      if (i < 1600) {
        int r = i / 25, k2 = i - r * 25;
        int row = min(t0 + r, NTREE - 1);
        pt2 = *(const float2*)(tags + ((size_t)row * CCH + c) * TAGD + 2 * k2);
      }
    }
#pragma unroll
    for (int s = 0; s < 8; ++s) {
      int i = tid + 640 * s;
      if (i < 4800) {
        int r = i / 75, k4 = i - (i / 75) * 75;
        f16* p = xle + r * 360 + 4 * k4;
        p[0] = (f16)pe[s].x; p[1] = (f16)pe[s].y; p[2] = (f16)pe[s].z; p[3] = (f16)pe[s].w;
      }
    }
#pragma unroll
    for (int s = 0; s < 2; ++s) {
      int i = tid + 640 * s;
      if (i < 1600) {
        int r = i / 25, k2 = i - (i / 25) * 25;
        xle[r * 360 + 300 + 2 * k2]     = (f16)pt[s].x;
        xle[r * 360 + 300 + 2 * k2 + 1] = (f16)pt[s].y;
      }
    }
    {
      int i = tid + 1280;
      if (i < 1600) {
        int r = i / 25, k2 = i - (i / 25) * 25;
        xle[r * 360 + 300 + 2 * k2]     = (f16)pt2.x;
        xle[r * 360 + 300 + 2 * k2 + 1] = (f16)pt2.y;
      }
    }
  }
  if (tid < 64) {
    xle[tid * 360 + 350] = (f16)0.0f;
    xle[tid * 360 + 351] = (f16)0.0f;
  }
  __syncthreads();

  // ---- phase 2: leaf GEMM K=352
  f32x4 acc[3][4];
#pragma unroll
  for (int g = 0; g < 3; ++g)
#pragma unroll
    for (int m = 0; m < 4; ++m) acc[g][m] = 0.f;

  for (int kt = 0; kt < KT_L; ++kt) {
    f16x8 a0 = *(const f16x8*)(xle + kt * 32 + acol8 + (arow)      * 360);
    f16x8 a1 = *(const f16x8*)(xle + kt * 32 + acol8 + (16 + arow) * 360);
    f16x8 a2 = *(const f16x8*)(xle + kt * 32 + acol8 + (32 + arow) * 360);
    f16x8 a3 = *(const f16x8*)(xle + kt * 32 + acol8 + (48 + arow) * 360);
#pragma unroll
    for (int g = 0; g < 3; ++g) {
      f16x8 b = WL[(kt * NTILE + g * 10 + w) * 64 + lane];
      acc[g][0] = __builtin_amdgcn_mfma_f32_16x16x32_f16(a0, b, acc[g][0], 0, 0, 0);
      acc[g][1] = __builtin_amdgcn_mfma_f32_16x16x32_f16(a1, b, acc[g][1], 0, 0, 0);
      acc[g][2] = __builtin_amdgcn_mfma_f32_16x16x32_f16(a2, b, acc[g][2], 0, 0, 0);
      acc[g][3] = __builtin_amdgcn_mfma_f32_16x16x32_f16(a3, b, acc[g][3], 0, 0, 0);
    }
  }
  __syncthreads();  // all xle reads done; buf may now be rewritten as xch

  // ---- phase 3: build x_child in aliased buffer
  {
    const float bLr = BIAS[j], bLz = BIAS[160 + j];
    const float bLi = BIAS[320 + j], bLh = BIAS[480 + j];
#pragma unroll
    for (int m = 0; m < 4; ++m)
#pragma unroll
      for (int q = 0; q < 4; ++q) {
        int row = 16 * m + qrow + q;
        float rg = sigmoid_f(acc[0][m][q] + bLr);
        float zg = sigmoid_f(acc[1][m][q] + bLz);
        float ng = tanh_f(acc[2][m][q] + bLi + rg * bLh);
        if (jok) xch[row * 264 + j] = (f16)((1.0f - zg) * ng);  // h0 = 0
      }
  }
  for (int i = tid; i < 64 * 25; i += 640) {
    int r = i / 25, k2 = i - r * 25;
    int row = min(t0 + r, NTREE - 1);
    float2 v = *(const float2*)(tags + ((size_t)row * CCH + c) * TAGD + 2 * k2);
    xch[r * 264 + 152 + 2 * k2] = (f16)v.x;
    xch[r * 264 + 153 + 2 * k2] = (f16)v.y;
  }
  for (int i = tid; i < 64 * 25; i += 640) {
    int r = i / 25, k2 = i - r * 25;
    int row = min(t0 + r, NTREE - 1);
    float2 v = *(const float2*)(tag_parent + (size_t)row * TAGD + 2 * k2);
    xch[r * 264 + 202 + 2 * k2] = (f16)v.x;
    xch[r * 264 + 203 + 2 * k2] = (f16)v.y;
  }
  for (int i = tid; i < 64 * 6; i += 640) {
    int r = i / 6, k = i - r * 6;
    int col = (k < 2) ? (150 + k) : (250 + k);  // 150,151,252..255
    xch[r * 264 + col] = (f16)0.0f;
  }
  __syncthreads();

  // ---- phase 4: x-GEMM K=256
#pragma unroll
  for (int g = 0; g < 3; ++g)
#pragma unroll
    for (int m = 0; m < 4; ++m) acc[g][m] = 0.f;

  for (int kt = 0; kt < KT_I; ++kt) {
    f16x8 a0 = *(const f16x8*)(xch + kt * 32 + acol8 + (arow)      * 264);
    f16x8 a1 = *(const f16x8*)(xch + kt * 32 + acol8 + (16 + arow) * 264);
    f16x8 a2 = *(const f16x8*)(xch + kt * 32 + acol8 + (32 + arow) * 264);
    f16x8 a3 = *(const f16x8*)(xch + kt * 32 + acol8 + (48 + arow) * 264);
#pragma unroll
    for (int g = 0; g < 3; ++g) {
      f16x8 b = WI[(kt * NTILE + g * 10 + w) * 64 + lane];
      acc[g][0] = __builtin_amdgcn_mfma_f32_16x16x32_f16(a0, b, acc[g][0], 0, 0, 0);
      acc[g][1] = __builtin_amdgcn_mfma_f32_16x16x32_f16(a1, b, acc[g][1], 0, 0, 0);
      acc[g][2] = __builtin_amdgcn_mfma_f32_16x16x32_f16(a2, b, acc[g][2], 0, 0, 0);
      acc[g][3] = __builtin_amdgcn_mfma_f32_16x16x32_f16(a3, b, acc[g][3], 0, 0, 0);
    }
  }

  // ---- phase 5: bake b_ih_child, store fragment-ordered gi (tail-guarded)
  {
    const float bi[3] = {BIAS[12 * 160 + j], BIAS[13 * 160 + j], BIAS[6 * 160 + j]};
#pragma unroll
    for (int m = 0; m < 4; ++m) {
      if (t0 + 16 * m < NTREE) {
        int tg = blk * 4 + m;
        char* base = ws + OFF_DATA + (size_t)c * C_STRIDE + (size_t)tg * TG_BYTES +
                     (size_t)lane * 8;
#pragma unroll
        for (int g = 0; g < 3; ++g) {
          f16x4 v;
#pragma unroll
          for (int q = 0; q < 4; ++q) v[q] = (f16)(acc[g][m][q] + bi[g]);
          *(f16x4*)(base + (size_t)(g * 10 + w) * 512) = v;
        }
      }
    }
  }
}

// ---------------- fold13: h double-buffer -> ONE barrier per step ----------------
__global__ __launch_bounds__(640, 1)
void fold13_kernel(const char* __restrict__ ws,
                   float* __restrict__ out) {
  __shared__ f16 hls[2 * 80 * 168];   // 53760 B; step c reads buf[c&1], writes buf[(c+1)&1]

  const f16x8* WH   = (const f16x8*)(ws + OFF_WH);
  const f16x8* WN   = (const f16x8*)(ws + OFF_WN);
  const float* BIAS = (const float*)(ws + OFF_BIAS);

  const int tid = threadIdx.x, lane = tid & 63, w = tid >> 6;  // w: 0..9
  const int blk = blockIdx.x, t0 = blk * 80;
  const int arow = lane & 15, acol8 = (lane >> 4) * 8, qrow = (lane >> 4) * 4;
  const int j = w * 16 + arow;
  const bool jok = j < MEMD;

  const float bhr = BIAS[14 * 160 + j], bhz = BIAS[15 * 160 + j], bhn = BIAS[7 * 160 + j];
  const float bNr = BIAS[8 * 160 + j],  bNz = BIAS[9 * 160 + j];
  const float bNi = BIAS[10 * 160 + j], bNh = BIAS[11 * 160 + j];

  // zero pad cols 150..167 in BOTH buffers (never h-written; gates cover rest)
  for (int i = tid; i < 2 * 80 * 18; i += 640) {
    int b = i / (80 * 18), rem = i - b * (80 * 18);
    int r = rem / 18;
    hls[b * 80 * 168 + r * 168 + 150 + (rem - r * 18)] = (f16)0.0f;
  }

  f16x8 whr[5], whz[5], whn[5];
#pragma unroll
  for (int kt = 0; kt < KT_H; ++kt) {
    whr[kt] = WH[(kt * NTILE + w) * 64 + lane];
    whz[kt] = WH[(kt * NTILE + 10 + w) * 64 + lane];
    whn[kt] = WH[(kt * NTILE + 20 + w) * 64 + lane];
  }

  const char* gbase = ws + OFF_DATA + (size_t)(blk * 5) * TG_BYTES +
                      (size_t)w * 512 + (size_t)lane * 8;

  f32x4 hp[5];
#pragma unroll
  for (int m = 0; m < 5; ++m) hp[m] = 0.f;

#pragma unroll
  for (int c = 0; c < CCH; ++c) {
    // gi(c) loads; GEMM below covers their latency
    f16x4 gbuf[15];
#pragma unroll
    for (int m = 0; m < 5; ++m)
#pragma unroll
      for (int g = 0; g < 3; ++g)
        gbuf[m * 3 + g] = *(const f16x4*)(gbase + (size_t)c * C_STRIDE +
                                          (size_t)m * TG_BYTES + (size_t)g * 5120);

    const f16* hcur = hls + (c & 1) * 80 * 168;
    f16*       hnxt = hls + ((c + 1) & 1) * 80 * 168;

    f32x4 aR[5], aZ[5], aNh[5];
#pragma unroll
    for (int m = 0; m < 5; ++m) { aR[m] = 0.f; aZ[m] = 0.f; aNh[m] = 0.f; }

    if (c != 0) {  // c=0: h=0 -> gh contribution zero; skip GEMM
#pragma unroll
      for (int kt = 0; kt < KT_H; ++kt) {
        const f16* ab = hcur + kt * 32 + acol8;
#pragma unroll
        for (int m = 0; m < 5; ++m) {
          f16x8 a = *(const f16x8*)(ab + (16 * m + arow) * 168);
          aR[m]  = __builtin_amdgcn_mfma_f32_16x16x32_f16(a, whr[kt], aR[m], 0, 0, 0);
          aZ[m]  = __builtin_amdgcn_mfma_f32_16x16x32_f16(a, whz[kt], aZ[m], 0, 0, 0);
          aNh[m] = __builtin_amdgcn_mfma_f32_16x16x32_f16(a, whn[kt], aNh[m], 0, 0, 0);
        }
      }
    }

    // gates: write NEW h to the OTHER buffer (prev step's barrier separates the
    // WAR vs step c-1's GEMM reads of hnxt)
#pragma unroll
    for (int m = 0; m < 5; ++m)
#pragma unroll
      for (int q = 0; q < 4; ++q) {
        int row = 16 * m + qrow + q;
        float rg = sigmoid_f((float)gbuf[m * 3 + 0][q] + aR[m][q] + bhr);
        float zg = sigmoid_f((float)gbuf[m * 3 + 1][q] + aZ[m][q] + bhz);
        float ng = tanh_f((float)gbuf[m * 3 + 2][q] + rg * (aNh[m][q] + bhn));
        float h  = (1.0f - zg) * ng + zg * hp[m][q];
        hp[m][q] = h;
        if (jok) hnxt[row * 168 + j] = (f16)h;
      }
    __syncthreads();  // single barrier per step
  }

  // node GRU: final h lives in buf[8&1] = buf0
  const f16* hfin = hls;
  f32x4 aR[5], aZ[5], aNh[5];
#pragma unroll
  for (int m = 0; m < 5; ++m) { aR[m] = 0.f; aZ[m] = 0.f; aNh[m] = 0.f; }
  for (int kt = 0; kt < KT_N; ++kt) {
    f16x8 br = WN[(kt * NTILE + w) * 64 + lane];
    f16x8 bz = WN[(kt * NTILE + 10 + w) * 64 + lane];
    f16x8 bn = WN[(kt * NTILE + 20 + w) * 64 + lane];
    const f16* ab = hfin + kt * 32 + acol8;
#pragma unroll
    for (int m = 0; m < 5; ++m) {
      f16x8 a = *(const f16x8*)(ab + (16 * m + arow) * 168);
      aR[m]  = __builtin_amdgcn_mfma_f32_16x16x32_f16(a, br, aR[m], 0, 0, 0);
      aZ[m]  = __builtin_amdgcn_mfma_f32_16x16x32_f16(a, bz, aZ[m], 0, 0, 0);
      aNh[m] = __builtin_amdgcn_mfma_f32_16x16x32_f16(a, bn, aNh[m], 0, 0, 0);
    }
  }
#pragma unroll
  for (int m = 0; m < 5; ++m)
#pragma unroll
    for (int q = 0; q < 4; ++q) {
      int row = 16 * m + qrow + q;
      float rg = sigmoid_f(aR[m][q] + bNr);
      float zg = sigmoid_f(aZ[m][q] + bNz);
      float ng = tanh_f(bNi + rg * (aNh[m][q] + bNh));
      float o  = (1.0f - zg) * ng + zg * hp[m][q];
      if (jok) out[(size_t)(t0 + row) * MEMD + j] = o;
    }
}

// ================= R2 fallback (proven) =================
namespace r2 {

__global__ __launch_bounds__(640)
void leaf_kernel(const float* __restrict__ embs,
                 const float* __restrict__ tags,
                 char* __restrict__ ws) {
  __shared__ f16 xle[80 * 360];
  const f16x8* WL   = (const f16x8*)(ws + OFF_WL);
  const float* BIAS = (const float*)(ws + OFF_BIAS);
  f16* hws = (f16*)(ws + OFF_DATA);

  const int tid = threadIdx.x, lane = tid & 63, w = tid >> 6;
  const int c = blockIdx.y, t0 = blockIdx.x * 80;
  const int arow = lane & 15, acol8 = (lane >> 4) * 8, qrow = (lane >> 4) * 4;
  const int j = w * 16 + (lane & 15);

  for (int i = tid; i < 80 * 150; i += 640) {
    int r = i / 150, k2 = i - r * 150;
    float2 v = *(const float2*)(embs + ((size_t)(t0 + r) * CCH + c) * WORD + 2 * k2);
    xle[r * 360 + 2 * k2]     = (f16)v.x;
    xle[r * 360 + 2 * k2 + 1] = (f16)v.y;
  }
  for (int i = tid; i < 80 * 25; i += 640) {
    int r = i / 25, k2 = i - r * 25;
    float2 v = *(const float2*)(tags + ((size_t)(t0 + r) * CCH + c) * TAGD + 2 * k2);
    xle[r * 360 + 300 + 2 * k2]     = (f16)v.x;
    xle[r * 360 + 300 + 2 * k2 + 1] = (f16)v.y;
  }
  for (int i = tid; i < 80; i += 640) {
    xle[i * 360 + 350] = (f16)0.0f;
    xle[i * 360 + 351] = (f16)0.0f;
  }
  __syncthreads();

  f32x4 aR[5], aZ[5], aN[5];
#pragma unroll
  for (int m = 0; m < 5; ++m) { aR[m] = 0.f; aZ[m] = 0.f; aN[m] = 0.f; }
  for (int kt = 0; kt < KT_L; ++kt) {
    f16x8 br = WL[(kt * NTILE + w) * 64 + lane];
    f16x8 bz = WL[(kt * NTILE + 10 + w) * 64 + lane];
    f16x8 bn = WL[(kt * NTILE + 20 + w) * 64 + lane];
    const f16* ab = xle + kt * 32 + acol8;
#pragma unroll
    for (int m = 0; m < 5; ++m) {
      f16x8 a = *(const f16x8*)(ab + (16 * m + arow) * 360);
      aR[m] = __builtin_amdgcn_mfma_f32_16x16x32_f16(a, br, aR[m], 0, 0, 0);
      aZ[m] = __builtin_amdgcn_mfma_f32_16x16x32_f16(a, bz, aZ[m], 0, 0, 0);
      aN[m] = __builtin_amdgcn_mfma_f32_16x16x32_f16(a, bn, aN[m], 0, 0, 0);
    }
  }
  const float bLr = BIAS[j], bLz = BIAS[160 + j], bLi = BIAS[320 + j], bLh = BIAS[480 + j];
#pragma unroll
  for (int m = 0; m < 5; ++m) {
#pragma unroll
    for (int q = 0; q < 4; ++q) {
      int row = 16 * m + qrow + q;
      float rg = sigmoid_f(aR[m][q] + bLr);
      float zg = sigmoid_f(aZ[m][q] + bLz);
      float ng = tanh_f(aN[m][q] + bLi + rg * bLh);
      float h  = (1.0f - zg) * ng;
      if (j < HW_S)
        hws[((size_t)c * NTREE + t0 + row) * HW_S + j] = (f16)(j < MEMD ? h : 0.0f);
    }
  }
}

__global__ __launch_bounds__(640)
void fold_kernel(const float* __restrict__ tags,
                 const float* __restrict__ tag_parent,
                 const char* __restrict__ ws,
                 float* __restrict__ out) {
  extern __shared__ char fsm[];
  f16* xch0 = (f16*)fsm;
  f16* xch1 = xch0 + 80 * 264;
  f16* hls  = xch1 + 80 * 264;

  const f16x8* WI   = (const f16x8*)(ws + OFF_WI);
  const f16x8* WH   = (const f16x8*)(ws + OFF_WH);
  const f16x8* WN   = (const f16x8*)(ws + OFF_WN);
  const float* BIAS = (const float*)(ws + OFF_BIAS);
  const f16*   hws  = (const f16*)(ws + OFF_DATA);

  const int tid = threadIdx.x, lane = tid & 63, w = tid >> 6;
  const int t0 = blockIdx.x * 80;
  const int arow = lane & 15, acol8 = (lane >> 4) * 8, qrow = (lane >> 4) * 4;
  const int j = w * 16 + (lane & 15);
  const bool jok = j < MEMD;

  const float bCr = BIAS[4 * 160 + j], bCz = BIAS[5 * 160 + j];
  const float bCi = BIAS[6 * 160 + j], bCh = BIAS[7 * 160 + j];
  const float bNr = BIAS[8 * 160 + j], bNz = BIAS[9 * 160 + j];
  const float bNi = BIAS[10 * 160 + j], bNh = BIAS[11 * 160 + j];

  for (int i = tid; i < 1680; i += 640) ((int4*)hls)[i] = make_int4(0, 0, 0, 0);
  for (int i = tid; i < 80 * 25; i += 640) {
    int r = i / 25, k2 = i - r * 25;
    float2 v = *(const float2*)(tag_parent + (size_t)(t0 + r) * TAGD + 2 * k2);
    f16 a = (f16)v.x, b = (f16)v.y;
    xch0[r * 264 + 202 + 2 * k2] = a; xch0[r * 264 + 203 + 2 * k2] = b;
    xch1[r * 264 + 202 + 2 * k2] = a; xch1[r * 264 + 203 + 2 * k2] = b;
  }
  for (int i = tid; i < 80 * 4; i += 640) {
    int r = i >> 2, k = i & 3;
    xch0[r * 264 + 252 + k] = (f16)0.0f;
    xch1[r * 264 + 252 + k] = (f16)0.0f;
  }
#pragma unroll
  for (int s = 0; s < 3; ++s) {
    int i = tid + 640 * s;
    if (i < 1520) {
      int r = i / 19, q = i - r * 19;
      *(f16x8*)(xch0 + r * 264 + 8 * q) =
          *(const f16x8*)(hws + ((size_t)(t0 + r)) * HW_S + 8 * q);
    }
  }
#pragma unroll
  for (int s = 0; s < 4; ++s) {
    int i = tid + 640 * s;
    if (i < 2000) {
      int r = i / 25, k2 = i - r * 25;
      float2 v = *(const float2*)(tags + ((size_t)(t0 + r) * CCH) * TAGD + 2 * k2);
      xch0[r * 264 + 152 + 2 * k2] = (f16)v.x;
      xch0[r * 264 + 153 + 2 * k2] = (f16)v.y;
    }
  }
  __syncthreads();

  f32x4 hp[5];
#pragma unroll
  for (int m = 0; m < 5; ++m) hp[m] = 0.f;

  f16* xc = xch0;
  f16* xa = xch1;

  for (int c = 0; c < CCH; ++c) {
    f16x8 ph[3];
    float2 pt[4];
    if (c < 7) {
#pragma unroll
      for (int s = 0; s < 3; ++s) {
        int i = tid + 640 * s;
        if (i < 1520) {
          int r = i / 19, q = i - r * 19;
          ph[s] = *(const f16x8*)(hws + ((size_t)(c + 1) * NTREE + t0 + r) * HW_S + 8 * q);
        }
      }
#pragma unroll
      for (int s = 0; s < 4; ++s) {
        int i = tid + 640 * s;
        if (i < 2000) {
          int r = i / 25, k2 = i - r * 25;
          pt[s] = *(const float2*)(tags + ((size_t)(t0 + r) * CCH + (c + 1)) * TAGD + 2 * k2);
        }
      }
    }

    f32x4 aR[5], aZ[5], aNi[5], aNh[5];
#pragma unroll
    for (int m = 0; m < 5; ++m) { aR[m] = 0.f; aZ[m] = 0.f; aNi[m] = 0.f; aNh[m] = 0.f; }
    for (int kt = 0; kt < KT_I; ++kt) {
      f16x8 br = WI[(kt * NTILE + w) * 64 + lane];
      f16x8 bz = WI[(kt * NTILE + 10 + w) * 64 + lane];
      f16x8 bn = WI[(kt * NTILE + 20 + w) * 64 + lane];
      const f16* ab = xc + kt * 32 + acol8;
#pragma unroll
      for (int m = 0; m < 5; ++m) {
        f16x8 a = *(const f16x8*)(ab + (16 * m + arow) * 264);
        aR[m]  = __builtin_amdgcn_mfma_f32_16x16x32_f16(a, br, aR[m], 0, 0, 0);
        aZ[m]  = __builtin_amdgcn_mfma_f32_16x16x32_f16(a, bz, aZ[m], 0, 0, 0);
        aNi[m] = __builtin_amdgcn_mfma_f32_16x16x32_f16(a, bn, aNi[m], 0, 0, 0);
      }
    }
    for (int kt = 0; kt < KT_H; ++kt) {
      f16x8 br = WH[(kt * NTILE + w) * 64 + lane];
      f16x8 bz = WH[(kt * NTILE + 10 + w) * 64 + lane];
      f16x8 bn = WH[(kt * NTILE + 20 + w) * 64 + lane];
      const f16* ab = hls + kt * 32 + acol8;
#pragma unroll
      for (int m = 0; m < 5; ++m) {
        f16x8 a = *(const f16x8*)(ab + (16 * m + arow) * 168);
        aR[m]  = __builtin_amdgcn_mfma_f32_16x16x32_f16(a, br, aR[m], 0, 0, 0);
        aZ[m]  = __builtin_amdgcn_mfma_f32_16x16x32_f16(a, bz, aZ[m], 0, 0, 0);
        aNh[m] = __builtin_amdgcn_mfma_f32_16x16x32_f16(a, bn, aNh[m], 0, 0, 0);
      }
    }
    __syncthreads();

    if (c < 7) {
#pragma unroll
      for (int s = 0; s < 3; ++s) {
        int i = tid + 640 * s;
        if (i < 1520) {
          int r = i / 19, q = i - r * 19;
          *(f16x8*)(xa + r * 264 + 8 * q) = ph[s];
        }
      }
#pragma unroll
      for (int s = 0; s < 4; ++s) {
        int i = tid + 640 * s;
        if (i < 2000) {
          int r = i / 25, k2 = i - r * 25;
          xa[r * 264 + 152 + 2 * k2] = (f16)pt[s].x;
          xa[r * 264 + 153 + 2 * k2] = (f16)pt[s].y;
        }
      }
    }

#pragma unroll
    for (int m = 0; m < 5; ++m) {
#pragma unroll
      for (int q = 0; q < 4; ++q) {
        int row = 16 * m + qrow + q;
        float rg = sigmoid_f(aR[m][q] + bCr);
        float zg = sigmoid_f(aZ[m][q] + bCz);
        float ng = tanh_f(aNi[m][q] + bCi + rg * (aNh[m][q] + bCh));
        float h  = (1.0f - zg) * ng + zg * hp[m][q];
        hp[m][q] = h;
        if (jok) hls[row * 168 + j] = (f16)h;
      }
    }
    __syncthreads();
    f16* tsw = xc; xc = xa; xa = tsw;
  }

  f32x4 aR[5], aZ[5], aNh[5];
#pragma unroll
  for (int m = 0; m < 5; ++m) { aR[m] = 0.f; aZ[m] = 0.f; aNh[m] = 0.f; }
  for (int kt = 0; kt < KT_N; ++kt) {
    f16x8 br = WN[(kt * NTILE + w) * 64 + lane];
    f16x8 bz = WN[(kt * NTILE + 10 + w) * 64 + lane];
    f16x8 bn = WN[(kt * NTILE + 20 + w) * 64 + lane];
    const f16* ab = hls + kt * 32 + acol8;
#pragma unroll
    for (int m = 0; m < 5; ++m) {
      f16x8 a = *(const f16x8*)(ab + (16 * m + arow) * 168);
      aR[m]  = __builtin_amdgcn_mfma_f32_16x16x32_f16(a, br, aR[m], 0, 0, 0);
      aZ[m]  = __builtin_amdgcn_mfma_f32_16x16x32_f16(a, bz, aZ[m], 0, 0, 0);
      aNh[m] = __builtin_amdgcn_mfma_f32_16x16x32_f16(a, bn, aNh[m], 0, 0, 0);
    }
  }
#pragma unroll
  for (int m = 0; m < 5; ++m) {
#pragma unroll
    for (int q = 0; q < 4; ++q) {
      int row = 16 * m + qrow + q;
      float rg = sigmoid_f(aR[m][q] + bNr);
      float zg = sigmoid_f(aZ[m][q] + bNz);
      float ng = tanh_f(bNi + rg * (aNh[m][q] + bNh));
      float o  = (1.0f - zg) * ng + zg * hp[m][q];
      if (jok) out[(size_t)(t0 + row) * MEMD + j] = o;
    }
  }
}

}  // namespace r2

}  // namespace

extern "C" void kernel_launch(void* const* d_in, const int* in_sizes, int n_in,
                              void* d_out, int out_size, void* d_ws, size_t ws_size,
                              hipStream_t stream) {
  const float* embs       = (const float*)d_in[0];
  const float* tags       = (const float*)d_in[1];
  const float* tag_parent = (const float*)d_in[2];
  const float* w_ih_leaf  = (const float*)d_in[3];
  // d_in[4] w_hh_leaf unused (h0 = 0)
  const float* b_ih_leaf  = (const float*)d_in[5];
  const float* b_hh_leaf  = (const float*)d_in[6];
  const float* w_ih_child = (const float*)d_in[7];
  const float* w_hh_child = (const float*)d_in[8];
  const float* b_ih_child = (const float*)d_in[9];
  const float* b_hh_child = (const float*)d_in[10];
  // d_in[11] w_ih_node unused (x = 0)
  const float* w_hh_node  = (const float*)d_in[12];
  const float* b_ih_node  = (const float*)d_in[13];
  const float* b_hh_node  = (const float*)d_in[14];
  float* out = (float*)d_out;
  char*  ws  = (char*)d_ws;

  prep_kernel<<<228, 256, 0, stream>>>(w_ih_leaf, b_ih_leaf, b_hh_leaf,
                                       w_ih_child, w_hh_child, b_ih_child, b_hh_child,
                                       w_hh_node, b_ih_node, b_hh_node, ws);

  if (ws_size >= WS_R3) {
    leaf12_kernel<<<dim3(LBLK, CCH), 640, 0, stream>>>(embs, tags, tag_parent, ws);
    fold13_kernel<<<NBLK, 640, 0, stream>>>(ws, out);
  } else {
    r2::leaf_kernel<<<dim3(250, CCH), 640, 0, stream>>>(embs, tags, ws);
    constexpr int FOLD_LDS = (2 * 80 * 264 + 80 * 168) * 2;  // 111360
    hipFuncSetAttribute((const void*)r2::fold_kernel,
                        hipFuncAttributeMaxDynamicSharedMemorySize, FOLD_LDS);
    r2::fold_kernel<<<250, 640, FOLD_LDS, stream>>>(tags, tag_parent, ws, out);
  }
}